// Round 18
// baseline (109.657 us; speedup 1.0000x reference)
//
#include <hip/hip_runtime.h>

typedef short bf8 __attribute__((ext_vector_type(8)));   // 8 bf16 in 4 VGPRs
typedef float f32x4 __attribute__((ext_vector_type(4)));
typedef float f32x16 __attribute__((ext_vector_type(16)));
typedef int i32x4 __attribute__((ext_vector_type(4)));

__device__ __forceinline__ ushort f2b(float f) {
  unsigned x = __builtin_bit_cast(unsigned, f);
  unsigned r = (x + 0x7fffu + ((x >> 16) & 1u)) >> 16;
  return (ushort)r;
}
__device__ __forceinline__ float b2f(ushort u) {
  unsigned x = ((unsigned)u) << 16;
  return __builtin_bit_cast(float, x);
}

__device__ __forceinline__ f32x4 mfma16(bf8 a, bf8 b, f32x4 c) {
  return __builtin_amdgcn_mfma_f32_16x16x32_bf16(a, b, c, 0, 0, 0);
}
__device__ __forceinline__ f32x16 mfma32(bf8 a, bf8 b, f32x16 c) {
  return __builtin_amdgcn_mfma_f32_32x32x16_bf16(a, b, c, 0, 0, 0);
}

__device__ __forceinline__ float fexp2(float x) {
#if __has_builtin(__builtin_amdgcn_exp2f)
  return __builtin_amdgcn_exp2f(x);
#else
  return exp2f(x);
#endif
}

__device__ __forceinline__ uint cvtpk(float lo, float hi_) {
  uint r;
  asm("v_cvt_pk_bf16_f32 %0, %1, %2" : "=v"(r) : "v"(lo), "v"(hi_));
  return r;
}
__device__ __forceinline__ void plswap(uint& a, uint& b) {
  asm("v_permlane32_swap_b32 %0, %1" : "+v"(a), "+v"(b));
}

__device__ __forceinline__ void gload16(const ushort* g, ushort* l) {
  __builtin_amdgcn_global_load_lds(
      (const __attribute__((address_space(1))) void*)g,
      (__attribute__((address_space(3))) void*)l, 16, 0, 0);
}

// ---------------- prep1: cast x (f32->bf16) + all weight transposes ------
__global__ __launch_bounds__(256) void prep1(
    const float* __restrict__ x, const float* __restrict__ wq,
    const float* __restrict__ wk, const float* __restrict__ wv,
    const float* __restrict__ wo, ushort* __restrict__ xb,
    ushort* __restrict__ wqkvT, ushort* __restrict__ woT) {
  __shared__ float tile[32][33];
  const int bid = blockIdx.x;
  if (bid < 4096) {
    const int i = (bid * 256 + threadIdx.x) * 4;
    float4 v = *(const float4*)(x + i);
    ushort4 o;
    o.x = f2b(v.x); o.y = f2b(v.y); o.z = f2b(v.z); o.w = f2b(v.w);
    *(ushort4*)(xb + i) = o;
    return;
  }
  int t = bid - 4096;  // 0..2559
  const float* src;
  ushort* dst;
  int N;
  if (t < 1024) {
    src = wq; dst = wqkvT; N = 1024;
  } else if (t < 1280) {
    src = wk; dst = wqkvT + 1024 * 1024; N = 256; t -= 1024;
  } else if (t < 1536) {
    src = wv; dst = wqkvT + 1280 * 1024; N = 256; t -= 1280;
  } else {
    src = wo; dst = woT; N = 1024; t -= 1536;
  }
  const int kx = (t & 31) * 32, nx = (t >> 5) * 32;
  const int tx = threadIdx.x & 31, ty = threadIdx.x >> 5;
#pragma unroll
  for (int i = ty; i < 32; i += 8)
    tile[i][tx] = src[(size_t)(kx + i) * N + nx + tx];
  __syncthreads();
#pragma unroll
  for (int i = ty; i < 32; i += 8)
    dst[(size_t)(nx + i) * 1024 + kx + tx] = f2b(tile[tx][i]);
}

// ------- GEMM C[M][N] = A[M][K]*Bt[N][K]^T; 64x128 tile, BK=64, 4 waves --
template <bool OUT_BF16>
__global__ __launch_bounds__(256) void gemm_bt(const ushort* __restrict__ A,
                                               const ushort* __restrict__ Bt,
                                               void* __restrict__ Cv, int M,
                                               int N, int K) {
  __shared__ ushort aL[64 * 64];    // 8 KB
  __shared__ ushort bL[128 * 64];   // 16 KB
  const int tid = threadIdx.x;
  const int wid = tid >> 6, lane = tid & 63;
  const int l15 = lane & 15, l4 = lane >> 4;
  const int bm = blockIdx.y * 64, bn = blockIdx.x * 128;
  const int wr = (wid & 1) * 32, wc = (wid >> 1) * 64;
  f32x4 acc[2][4] = {};
  for (int kb = 0; kb < K; kb += 64) {
    __syncthreads();
#pragma unroll
    for (int i = 0; i < 2; ++i) {  // A: 64x64 = 512 chunks, 2/thread
      const int e = (i * 256 + tid) * 8;
      const int r = e >> 6, c = e & 63;
      gload16(A + (size_t)(bm + r) * K + kb + c, &aL[i * 2048 + wid * 512]);
    }
#pragma unroll
    for (int i = 0; i < 4; ++i) {  // B: 128x64 = 1024 chunks, 4/thread
      const int e = (i * 256 + tid) * 8;
      const int r = e >> 6, c = e & 63;
      gload16(Bt + (size_t)(bn + r) * K + kb + c, &bL[i * 2048 + wid * 512]);
    }
    asm volatile("s_waitcnt vmcnt(0)" ::: "memory");
    __syncthreads();
    bf8 af[2][2], bfr[4][2];
#pragma unroll
    for (int i = 0; i < 2; ++i)
#pragma unroll
      for (int kk = 0; kk < 2; ++kk)
        af[i][kk] =
            *(const bf8*)&aL[(wr + i * 16 + l15) * 64 + kk * 32 + l4 * 8];
#pragma unroll
    for (int j = 0; j < 4; ++j)
#pragma unroll
      for (int kk = 0; kk < 2; ++kk)
        bfr[j][kk] =
            *(const bf8*)&bL[(wc + j * 16 + l15) * 64 + kk * 32 + l4 * 8];
#pragma unroll
    for (int kk = 0; kk < 2; ++kk)
#pragma unroll
      for (int i = 0; i < 2; ++i)
#pragma unroll
        for (int j = 0; j < 4; ++j)
          acc[i][j] = mfma16(af[i][kk], bfr[j][kk], acc[i][j]);
  }
#pragma unroll
  for (int i = 0; i < 2; ++i)
#pragma unroll
    for (int j = 0; j < 4; ++j)
#pragma unroll
      for (int r = 0; r < 4; ++r) {
        const size_t row = bm + wr + i * 16 + l4 * 4 + r;
        const size_t col = bn + wc + j * 16 + l15;
        if constexpr (OUT_BF16)
          ((ushort*)Cv)[row * N + col] = f2b(acc[i][j][r]);
        else
          ((float*)Cv)[row * N + col] = acc[i][j][r];
      }
}

// ---------------- prep2: RoPE for Q,K + V transpose ----------------
// Q is pre-scaled by 0.125*log2(e) so attention scores are in log2 domain.
__global__ __launch_bounds__(256) void prep2(const ushort* __restrict__ qkv,
                                             const float* __restrict__ fc,
                                             const float* __restrict__ fs,
                                             ushort* __restrict__ qh,
                                             ushort* __restrict__ kh,
                                             ushort* __restrict__ vT) {
  __shared__ ushort tile[64][65];
  if (blockIdx.x < 10240) {
    const int idx = blockIdx.x * 256 + threadIdx.x;  // 4096*640 total
    const int u = idx % 640;
    const int m = idx / 640;
    const int s = m & 2047, b = m >> 11;
    int col, j;
    if (u < 512) {
      j = u & 31;
      col = (u >> 5) * 64 + 2 * j;
    } else {
      j = (u - 512) & 31;
      col = 1024 + ((u - 512) >> 5) * 64 + 2 * j;
    }
    const uint pr = *(const uint*)(qkv + (size_t)m * 1536 + col);
    const float tr = b2f((ushort)(pr & 0xffff));
    const float ti = b2f((ushort)(pr >> 16));
    const float c = fc[s * 32 + j], sn = fs[s * 32 + j];
    float orr = tr * c - ti * sn;
    float oi = tr * sn + ti * c;
    if (u < 512) {
      orr *= 0.18033688f;  // (1/sqrt(64)) * log2(e)
      oi *= 0.18033688f;
      const uint w = (uint)f2b(orr) | ((uint)f2b(oi) << 16);
      *(uint*)(qh + ((size_t)(b * 16 + (u >> 5)) * 2048 + s) * 64 + 2 * j) = w;
    } else {
      const uint w = (uint)f2b(orr) | ((uint)f2b(oi) << 16);
      const int kv = (u - 512) >> 5;
      *(uint*)(kh + ((size_t)(b * 4 + kv) * 2048 + s) * 64 + 2 * j) = w;
    }
    return;
  }
  // V transpose: 256 blocks
  const int id = blockIdx.x - 10240;
  const int st = id & 31, kv = (id >> 5) & 3, b = id >> 7;
  const int tid = threadIdx.x;
  for (int e = tid; e < 4096; e += 256) {
    const int r = e >> 6, c = e & 63;
    tile[r][c] =
        qkv[(size_t)(b * 2048 + st * 64 + r) * 1536 + 1280 + kv * 64 + c];
  }
  __syncthreads();
  for (int e = tid; e < 4096; e += 256) {
    const int d = e >> 6, c = e & 63;
    vT[((size_t)(b * 4 + kv) * 64 + d) * 2048 + st * 64 + c] = tile[c][d];
  }
}

// ---------------- Flash attention v12: 1-barrier double-buffered supersteps
// 512 blocks x 256 thr (4 waves = 4 heads of one kv group, shared KV stage).
// Pairing t = half ? 63-p : p (per-CU work sum = 33 tiles). Superstep = 2
// 64-key subtiles; TWO parities of LDS buffers (64KB total). Protocol per
// superstep: vmcnt(0) [own stage(ss) landed] -> s_barrier [collective: all
// stage(ss) landed AND all iter ss-1 asteps done => parity ss-1 overwritable]
// -> stage(ss+1) into parity ss+1 (== ss-1) -> read frags parity ss ->
// lgkmcnt(0)+sched_barrier -> 2x astep2. ONE barrier/superstep; stage issue
// leads its vmcnt wait by a full compute phase. Epilogue reuses the K-buffer
// region (no staging outstanding, frags in regs). Fixed-max softmax.

#define MCONST 12.0f

__device__ __forceinline__ void astep2(const bf8 (&kfA)[4], const bf8 (&kfB)[4],
                                       const bf8 (&vfA)[4], const bf8 (&vfB)[4],
                                       const bf8 (&qf)[4], f32x16& o0,
                                       f32x16& o1, float& l, int k0, int qg,
                                       bool maskt, int hi) {
  f32x16 s0 = {}, s1 = {};
  __builtin_amdgcn_s_setprio(1);
#pragma unroll
  for (int ks = 0; ks < 4; ++ks) s0 = mfma32(kfA[ks], qf[ks], s0);
#pragma unroll
  for (int ks = 0; ks < 4; ++ks) s1 = mfma32(kfB[ks], qf[ks], s1);
  __builtin_amdgcn_s_setprio(0);
  if (maskt) {
#pragma unroll
    for (int r = 0; r < 16; ++r) {
      const int key = k0 + (r & 3) + 8 * (r >> 2) + 4 * hi;
      if (key > qg) s0[r] = -1e30f;
      if (key + 32 > qg) s1[r] = -1e30f;
    }
  }
  float t[16];
#pragma unroll
  for (int r = 0; r < 16; ++r) {
    s0[r] = fexp2(s0[r] - MCONST);
    s1[r] = fexp2(s1[r] - MCONST);
    t[r] = s0[r] + s1[r];
  }
#pragma unroll
  for (int st = 8; st > 0; st >>= 1)
#pragma unroll
    for (int r = 0; r < st; ++r) t[r] += t[r + st];
  l += t[0] + __shfl_xor(t[0], 32);
  bf8 pa[4];
  {
    uint a0 = cvtpk(s0[0], s0[1]), a1 = cvtpk(s0[2], s0[3]);
    uint b0 = cvtpk(s0[4], s0[5]), b1 = cvtpk(s0[6], s0[7]);
    plswap(a0, b0);
    plswap(a1, b1);
    i32x4 w = {(int)a0, (int)a1, (int)b0, (int)b1};
    pa[0] = __builtin_bit_cast(bf8, w);
    uint c0 = cvtpk(s0[8], s0[9]), c1 = cvtpk(s0[10], s0[11]);
    uint d0 = cvtpk(s0[12], s0[13]), d1 = cvtpk(s0[14], s0[15]);
    plswap(c0, d0);
    plswap(c1, d1);
    i32x4 w2 = {(int)c0, (int)c1, (int)d0, (int)d1};
    pa[1] = __builtin_bit_cast(bf8, w2);
  }
  {
    uint a0 = cvtpk(s1[0], s1[1]), a1 = cvtpk(s1[2], s1[3]);
    uint b0 = cvtpk(s1[4], s1[5]), b1 = cvtpk(s1[6], s1[7]);
    plswap(a0, b0);
    plswap(a1, b1);
    i32x4 w = {(int)a0, (int)a1, (int)b0, (int)b1};
    pa[2] = __builtin_bit_cast(bf8, w);
    uint c0 = cvtpk(s1[8], s1[9]), c1 = cvtpk(s1[10], s1[11]);
    uint d0 = cvtpk(s1[12], s1[13]), d1 = cvtpk(s1[14], s1[15]);
    plswap(c0, d0);
    plswap(c1, d1);
    i32x4 w2 = {(int)c0, (int)c1, (int)d0, (int)d1};
    pa[3] = __builtin_bit_cast(bf8, w2);
  }
  __builtin_amdgcn_s_setprio(1);
#pragma unroll
  for (int ks = 0; ks < 4; ++ks) o0 = mfma32(vfA[ks], pa[ks], o0);
#pragma unroll
  for (int ks = 0; ks < 4; ++ks) o1 = mfma32(vfB[ks], pa[ks], o1);
  __builtin_amdgcn_s_setprio(0);
}

__device__ __forceinline__ void tile_out(ushort* ow, const f32x16& o0,
                                         const f32x16& o1, float l, int b,
                                         int h, int qw, int l31, int hi,
                                         int lane, ushort* ao) {
  const float inv = 1.0f / l;
#pragma unroll
  for (int dt = 0; dt < 2; ++dt)
#pragma unroll
    for (int rq = 0; rq < 4; ++rq) {
      const f32x16& ac = dt ? o1 : o0;
      uint2 w;
      w.x = (uint)f2b(ac[rq * 4 + 0] * inv) |
            ((uint)f2b(ac[rq * 4 + 1] * inv) << 16);
      w.y = (uint)f2b(ac[rq * 4 + 2] * inv) |
            ((uint)f2b(ac[rq * 4 + 3] * inv) << 16);
      const int d = dt * 32 + 8 * rq + 4 * hi;
      *(uint2*)&ow[l31 * 66 + d] = w;
    }
  asm volatile("s_waitcnt lgkmcnt(0)" ::: "memory");
  __builtin_amdgcn_sched_barrier(0);
  const int rrow = lane >> 4;
  const int rcol = (lane & 15) * 4;
  const size_t gbase = ((size_t)b * 2048 + qw) * 1024 + h * 64;
#pragma unroll
  for (int i = 0; i < 8; ++i) {
    const int rw = i * 4 + rrow;
    uint2 v = *(const uint2*)&ow[rw * 66 + rcol];
    *(uint2*)&ao[gbase + (size_t)rw * 1024 + rcol] = v;
  }
}

__global__ __launch_bounds__(256) void attn_fwd(const ushort* __restrict__ qh,
                                                const ushort* __restrict__ kh,
                                                const ushort* __restrict__ vT,
                                                ushort* __restrict__ ao) {
  __shared__ ushort kls[2][2][4096];  // [parity][hf] K subtiles, 32KB
  __shared__ ushort vls[2][2][4096];  // [parity][hf] V subtiles, 32KB
  const int tid = threadIdx.x;
  const int wid = tid >> 6, lane = tid & 63;
  const int l31 = lane & 31, hi = lane >> 5;
  const int gid = blockIdx.x;  // 512
  const int bk = gid & 7;      // b*4 + kv (fixed per XCD -> KV L2-resident)
  const int b = bk >> 2, kv = bk & 3;
  const int rest = gid >> 3;   // 0..63
  const int p = rest & 31, half = rest >> 5;
  const int t = half ? (63 - p) : p;  // pairing: per-CU tile sum = 33
  const int h = kv * 4 + wid;
  const int n = (32 * t + 95) >> 6;   // 64-key tiles: 1..32
  const int nss = (n + 1) >> 1;       // 128-key supersteps: 1..16
  const int qg = t * 32 + l31;

  const ushort* kbase = kh + (size_t)(b * 4 + kv) * 2048 * 64;
  const ushort* vbase = vT + (size_t)(b * 4 + kv) * 64 * 2048;

  // wave w stages chunks {w, w+4} of tile j into [par][hf]
  auto stageTile = [&](int j, int par, int hf) {
    const int k0 = j * 64;
#pragma unroll
    for (int jj2 = 0; jj2 < 2; ++jj2) {
      const int jj = wid + jj2 * 4;
      const int i = jj * 64 + lane;
      const int r = i >> 3, s = i & 7;
      const int sw = (s ^ (r & 7)) << 3;
      gload16(kbase + (size_t)(k0 + r) * 64 + sw, kls[par][hf] + jj * 512);
      gload16(vbase + (size_t)r * 2048 + k0 + sw, vls[par][hf] + jj * 512);
    }
  };
  auto stageSS = [&](int ss) {
    const int par = ss & 1;
    const int j0 = 2 * ss;
    const int j1 = (2 * ss + 1 < n) ? (2 * ss + 1) : (n - 1);
    stageTile(j0, par, 0);
    stageTile(j1, par, 1);  // duplicate harmless when n odd (never consumed)
  };

  stageSS(0);

  bf8 qf[4];
  {
    const ushort* qb = qh + ((size_t)(b * 16 + h) * 2048 + qg) * 64 + hi * 8;
#pragma unroll
    for (int ks = 0; ks < 4; ++ks) qf[ks] = *(const bf8*)(qb + ks * 16);
  }

  f32x16 o0 = {}, o1 = {};
  float l = 0.f;
  const int sw0 = l31 & 7;

  for (int ss = 0; ss < nss; ++ss) {
    const int par = ss & 1;
    asm volatile("s_waitcnt vmcnt(0)" ::: "memory");  // own stage(ss) landed
    __builtin_amdgcn_s_barrier();  // all stage(ss) landed; all ss-1 asteps
                                   // done => parity ss+1 (==ss-1) overwritable
    asm volatile("" ::: "memory");
    if (ss + 1 < nss) stageSS(ss + 1);  // covered by reads+asteps below
    bf8 kfA[2][4], kfB[2][4], vfA[2][4], vfB[2][4];
#pragma unroll
    for (int hf = 0; hf < 2; ++hf)
#pragma unroll
      for (int ks = 0; ks < 4; ++ks) {
        const int c2 = 2 * ks + hi;
        const int off = (c2 ^ sw0) << 3;
        kfA[hf][ks] = *(const bf8*)&kls[par][hf][l31 * 64 + off];
        kfB[hf][ks] = *(const bf8*)&kls[par][hf][(32 + l31) * 64 + off];
        vfA[hf][ks] = *(const bf8*)&vls[par][hf][l31 * 64 + off];
        vfB[hf][ks] = *(const bf8*)&vls[par][hf][(32 + l31) * 64 + off];
      }
    asm volatile("s_waitcnt lgkmcnt(0)" ::: "memory");
    __builtin_amdgcn_sched_barrier(0);
    const int j0 = 2 * ss, j1 = 2 * ss + 1;
    astep2(kfA[0], kfB[0], vfA[0], vfB[0], qf, o0, o1, l, j0 * 64, qg,
           j0 == n - 1, hi);
    if (j1 < n)
      astep2(kfA[1], kfB[1], vfA[1], vfB[1], qf, o0, o1, l, j1 * 64, qg,
             j1 == n - 1, hi);
  }
  // epilogue: reuse K-buffer region as per-wave transpose scratch (no
  // staging outstanding; all frag reads drained into registers).
  ushort* ow = (ushort*)&kls[0][0][0] + wid * 2176;
  tile_out(ow, o0, o1, l, b, h, t * 32, l31, hi, lane, ao);
}

extern "C" void kernel_launch(void* const* d_in, const int* in_sizes, int n_in,
                              void* d_out, int out_size, void* d_ws,
                              size_t ws_size, hipStream_t stream) {
  (void)in_sizes; (void)n_in; (void)out_size; (void)ws_size;
  const float* x = (const float*)d_in[0];
  const float* wq = (const float*)d_in[1];
  const float* wk = (const float*)d_in[2];
  const float* wv = (const float*)d_in[3];
  const float* wo = (const float*)d_in[4];
  const float* fc = (const float*)d_in[5];
  const float* fs = (const float*)d_in[6];
  float* out = (float*)d_out;

  ushort* xb = (ushort*)d_ws;               // 4096x1024
  ushort* wqkvT = xb + 4194304;             // 1536x1024
  ushort* woT = wqkvT + 1572864;            // 1024x1024
  ushort* qkv = woT + 1048576;              // 4096x1536
  ushort* qh = qkv + 6291456;               // 32x2048x64
  ushort* kh = qh + 4194304;                // 8x2048x64
  ushort* vTb = kh + 1048576;               // 8x64x2048
  ushort* ao = vTb + 1048576;               // 4096x1024

  prep1<<<6656, 256, 0, stream>>>(x, wq, wk, wv, wo, xb, wqkvT, woT);
  gemm_bt<true><<<dim3(12, 64), 256, 0, stream>>>(xb, wqkvT, qkv, 4096, 1536, 1024);
  prep2<<<10496, 256, 0, stream>>>(qkv, fc, fs, qh, kh, vTb);
  attn_fwd<<<512, 256, 0, stream>>>(qh, kh, vTb, ao);
  gemm_bt<false><<<dim3(8, 64), 256, 0, stream>>>(ao, woT, out, 4096, 1024, 1024);
}

// Round 19
// 105.749 us; speedup vs baseline: 1.0370x; 1.0370x over previous
//
#include <hip/hip_runtime.h>

typedef short bf8 __attribute__((ext_vector_type(8)));   // 8 bf16 in 4 VGPRs
typedef float f32x4 __attribute__((ext_vector_type(4)));
typedef float f32x16 __attribute__((ext_vector_type(16)));
typedef int i32x4 __attribute__((ext_vector_type(4)));

__device__ __forceinline__ ushort f2b(float f) {
  unsigned x = __builtin_bit_cast(unsigned, f);
  unsigned r = (x + 0x7fffu + ((x >> 16) & 1u)) >> 16;
  return (ushort)r;
}
__device__ __forceinline__ float b2f(ushort u) {
  unsigned x = ((unsigned)u) << 16;
  return __builtin_bit_cast(float, x);
}

__device__ __forceinline__ f32x4 mfma16(bf8 a, bf8 b, f32x4 c) {
  return __builtin_amdgcn_mfma_f32_16x16x32_bf16(a, b, c, 0, 0, 0);
}
__device__ __forceinline__ f32x16 mfma32(bf8 a, bf8 b, f32x16 c) {
  return __builtin_amdgcn_mfma_f32_32x32x16_bf16(a, b, c, 0, 0, 0);
}

__device__ __forceinline__ float fexp2(float x) {
#if __has_builtin(__builtin_amdgcn_exp2f)
  return __builtin_amdgcn_exp2f(x);
#else
  return exp2f(x);
#endif
}

__device__ __forceinline__ uint cvtpk(float lo, float hi_) {
  uint r;
  asm("v_cvt_pk_bf16_f32 %0, %1, %2" : "=v"(r) : "v"(lo), "v"(hi_));
  return r;
}
__device__ __forceinline__ void plswap(uint& a, uint& b) {
  asm("v_permlane32_swap_b32 %0, %1" : "+v"(a), "+v"(b));
}

__device__ __forceinline__ void gload16(const ushort* g, ushort* l) {
  __builtin_amdgcn_global_load_lds(
      (const __attribute__((address_space(1))) void*)g,
      (__attribute__((address_space(3))) void*)l, 16, 0, 0);
}

// ---------------- prep1: cast x (f32->bf16) + all weight transposes ------
__global__ __launch_bounds__(256) void prep1(
    const float* __restrict__ x, const float* __restrict__ wq,
    const float* __restrict__ wk, const float* __restrict__ wv,
    const float* __restrict__ wo, ushort* __restrict__ xb,
    ushort* __restrict__ wqkvT, ushort* __restrict__ woT) {
  __shared__ float tile[32][33];
  const int bid = blockIdx.x;
  if (bid < 4096) {
    const int i = (bid * 256 + threadIdx.x) * 4;
    float4 v = *(const float4*)(x + i);
    ushort4 o;
    o.x = f2b(v.x); o.y = f2b(v.y); o.z = f2b(v.z); o.w = f2b(v.w);
    *(ushort4*)(xb + i) = o;
    return;
  }
  int t = bid - 4096;  // 0..2559
  const float* src;
  ushort* dst;
  int N;
  if (t < 1024) {
    src = wq; dst = wqkvT; N = 1024;
  } else if (t < 1280) {
    src = wk; dst = wqkvT + 1024 * 1024; N = 256; t -= 1024;
  } else if (t < 1536) {
    src = wv; dst = wqkvT + 1280 * 1024; N = 256; t -= 1280;
  } else {
    src = wo; dst = woT; N = 1024; t -= 1536;
  }
  const int kx = (t & 31) * 32, nx = (t >> 5) * 32;
  const int tx = threadIdx.x & 31, ty = threadIdx.x >> 5;
#pragma unroll
  for (int i = ty; i < 32; i += 8)
    tile[i][tx] = src[(size_t)(kx + i) * N + nx + tx];
  __syncthreads();
#pragma unroll
  for (int i = ty; i < 32; i += 8)
    dst[(size_t)(nx + i) * 1024 + kx + tx] = f2b(tile[tx][i]);
}

// ------- GEMM C[M][N] = A[M][K]*Bt[N][K]^T; 64x128 tile, BK=64, 4 waves --
// 1D grid with bijective XCD swizzle (nwg % 8 == 0): each XCD gets a
// contiguous chunk of M-panels -> A panels become XCD-L2-local.
template <bool OUT_BF16>
__global__ __launch_bounds__(256) void gemm_bt(const ushort* __restrict__ A,
                                               const ushort* __restrict__ Bt,
                                               void* __restrict__ Cv, int M,
                                               int N, int K, int nbx) {
  __shared__ ushort aL[64 * 64];    // 8 KB
  __shared__ ushort bL[128 * 64];   // 16 KB
  const int tid = threadIdx.x;
  const int wid = tid >> 6, lane = tid & 63;
  const int l15 = lane & 15, l4 = lane >> 4;
  const int qch = gridDim.x >> 3;
  const int sw = (blockIdx.x & 7) * qch + (blockIdx.x >> 3);
  const int bxi = sw % nbx, byi = sw / nbx;
  const int bm = byi * 64, bn = bxi * 128;
  const int wr = (wid & 1) * 32, wc = (wid >> 1) * 64;
  f32x4 acc[2][4] = {};
  for (int kb = 0; kb < K; kb += 64) {
    __syncthreads();
#pragma unroll
    for (int i = 0; i < 2; ++i) {  // A: 64x64 = 512 chunks, 2/thread
      const int e = (i * 256 + tid) * 8;
      const int r = e >> 6, c = e & 63;
      gload16(A + (size_t)(bm + r) * K + kb + c, &aL[i * 2048 + wid * 512]);
    }
#pragma unroll
    for (int i = 0; i < 4; ++i) {  // B: 128x64 = 1024 chunks, 4/thread
      const int e = (i * 256 + tid) * 8;
      const int r = e >> 6, c = e & 63;
      gload16(Bt + (size_t)(bn + r) * K + kb + c, &bL[i * 2048 + wid * 512]);
    }
    asm volatile("s_waitcnt vmcnt(0)" ::: "memory");
    __syncthreads();
    bf8 af[2][2], bfr[4][2];
#pragma unroll
    for (int i = 0; i < 2; ++i)
#pragma unroll
      for (int kk = 0; kk < 2; ++kk)
        af[i][kk] =
            *(const bf8*)&aL[(wr + i * 16 + l15) * 64 + kk * 32 + l4 * 8];
#pragma unroll
    for (int j = 0; j < 4; ++j)
#pragma unroll
      for (int kk = 0; kk < 2; ++kk)
        bfr[j][kk] =
            *(const bf8*)&bL[(wc + j * 16 + l15) * 64 + kk * 32 + l4 * 8];
#pragma unroll
    for (int kk = 0; kk < 2; ++kk)
#pragma unroll
      for (int i = 0; i < 2; ++i)
#pragma unroll
        for (int j = 0; j < 4; ++j)
          acc[i][j] = mfma16(af[i][kk], bfr[j][kk], acc[i][j]);
  }
#pragma unroll
  for (int i = 0; i < 2; ++i)
#pragma unroll
    for (int j = 0; j < 4; ++j)
#pragma unroll
      for (int r = 0; r < 4; ++r) {
        const size_t row = bm + wr + i * 16 + l4 * 4 + r;
        const size_t col = bn + wc + j * 16 + l15;
        if constexpr (OUT_BF16)
          ((ushort*)Cv)[row * N + col] = f2b(acc[i][j][r]);
        else
          ((float*)Cv)[row * N + col] = acc[i][j][r];
      }
}

// ---------------- prep2: RoPE for Q,K + V transpose ----------------
// Q is pre-scaled by 0.125*log2(e) so attention scores are in log2 domain.
__global__ __launch_bounds__(256) void prep2(const ushort* __restrict__ qkv,
                                             const float* __restrict__ fc,
                                             const float* __restrict__ fs,
                                             ushort* __restrict__ qh,
                                             ushort* __restrict__ kh,
                                             ushort* __restrict__ vT) {
  __shared__ ushort tile[64][65];
  if (blockIdx.x < 10240) {
    const int idx = blockIdx.x * 256 + threadIdx.x;  // 4096*640 total
    const int u = idx % 640;
    const int m = idx / 640;
    const int s = m & 2047, b = m >> 11;
    int col, j;
    if (u < 512) {
      j = u & 31;
      col = (u >> 5) * 64 + 2 * j;
    } else {
      j = (u - 512) & 31;
      col = 1024 + ((u - 512) >> 5) * 64 + 2 * j;
    }
    const uint pr = *(const uint*)(qkv + (size_t)m * 1536 + col);
    const float tr = b2f((ushort)(pr & 0xffff));
    const float ti = b2f((ushort)(pr >> 16));
    const float c = fc[s * 32 + j], sn = fs[s * 32 + j];
    float orr = tr * c - ti * sn;
    float oi = tr * sn + ti * c;
    if (u < 512) {
      orr *= 0.18033688f;  // (1/sqrt(64)) * log2(e)
      oi *= 0.18033688f;
      const uint w = (uint)f2b(orr) | ((uint)f2b(oi) << 16);
      *(uint*)(qh + ((size_t)(b * 16 + (u >> 5)) * 2048 + s) * 64 + 2 * j) = w;
    } else {
      const uint w = (uint)f2b(orr) | ((uint)f2b(oi) << 16);
      const int kv = (u - 512) >> 5;
      *(uint*)(kh + ((size_t)(b * 4 + kv) * 2048 + s) * 64 + 2 * j) = w;
    }
    return;
  }
  // V transpose: 256 blocks
  const int id = blockIdx.x - 10240;
  const int st = id & 31, kv = (id >> 5) & 3, b = id >> 7;
  const int tid = threadIdx.x;
  for (int e = tid; e < 4096; e += 256) {
    const int r = e >> 6, c = e & 63;
    tile[r][c] =
        qkv[(size_t)(b * 2048 + st * 64 + r) * 1536 + 1280 + kv * 64 + c];
  }
  __syncthreads();
  for (int e = tid; e < 4096; e += 256) {
    const int d = e >> 6, c = e & 63;
    vT[((size_t)(b * 4 + kv) * 64 + d) * 2048 + st * 64 + c] = tile[c][d];
  }
}

// ---------------- Flash attention v11 (R17 best): 128-key supersteps ------
// 512 blocks x 256 thr (4 waves = 4 heads of one kv group, shared KV stage).
// Pairing t = half ? 63-p : p (per-CU work sum = 33 tiles). Superstep = 2
// 64-key subtiles per barrier pair: stage 32KB (8 gloads/wave, uniform),
// vmcnt+barrier, read BOTH subtiles' frags, lgkm+barrier, stage next
// superstep, then two astep2 calls. Fixed-max softmax (log2 domain).

#define MCONST 12.0f

__device__ __forceinline__ void astep2(const bf8 (&kfA)[4], const bf8 (&kfB)[4],
                                       const bf8 (&vfA)[4], const bf8 (&vfB)[4],
                                       const bf8 (&qf)[4], f32x16& o0,
                                       f32x16& o1, float& l, int k0, int qg,
                                       bool maskt, int hi) {
  f32x16 s0 = {}, s1 = {};
  __builtin_amdgcn_s_setprio(1);
#pragma unroll
  for (int ks = 0; ks < 4; ++ks) s0 = mfma32(kfA[ks], qf[ks], s0);
#pragma unroll
  for (int ks = 0; ks < 4; ++ks) s1 = mfma32(kfB[ks], qf[ks], s1);
  __builtin_amdgcn_s_setprio(0);
  if (maskt) {
#pragma unroll
    for (int r = 0; r < 16; ++r) {
      const int key = k0 + (r & 3) + 8 * (r >> 2) + 4 * hi;
      if (key > qg) s0[r] = -1e30f;
      if (key + 32 > qg) s1[r] = -1e30f;
    }
  }
  float t[16];
#pragma unroll
  for (int r = 0; r < 16; ++r) {
    s0[r] = fexp2(s0[r] - MCONST);
    s1[r] = fexp2(s1[r] - MCONST);
    t[r] = s0[r] + s1[r];
  }
#pragma unroll
  for (int st = 8; st > 0; st >>= 1)
#pragma unroll
    for (int r = 0; r < st; ++r) t[r] += t[r + st];
  l += t[0] + __shfl_xor(t[0], 32);
  bf8 pa[4];
  {
    uint a0 = cvtpk(s0[0], s0[1]), a1 = cvtpk(s0[2], s0[3]);
    uint b0 = cvtpk(s0[4], s0[5]), b1 = cvtpk(s0[6], s0[7]);
    plswap(a0, b0);
    plswap(a1, b1);
    i32x4 w = {(int)a0, (int)a1, (int)b0, (int)b1};
    pa[0] = __builtin_bit_cast(bf8, w);
    uint c0 = cvtpk(s0[8], s0[9]), c1 = cvtpk(s0[10], s0[11]);
    uint d0 = cvtpk(s0[12], s0[13]), d1 = cvtpk(s0[14], s0[15]);
    plswap(c0, d0);
    plswap(c1, d1);
    i32x4 w2 = {(int)c0, (int)c1, (int)d0, (int)d1};
    pa[1] = __builtin_bit_cast(bf8, w2);
  }
  {
    uint a0 = cvtpk(s1[0], s1[1]), a1 = cvtpk(s1[2], s1[3]);
    uint b0 = cvtpk(s1[4], s1[5]), b1 = cvtpk(s1[6], s1[7]);
    plswap(a0, b0);
    plswap(a1, b1);
    i32x4 w = {(int)a0, (int)a1, (int)b0, (int)b1};
    pa[2] = __builtin_bit_cast(bf8, w);
    uint c0 = cvtpk(s1[8], s1[9]), c1 = cvtpk(s1[10], s1[11]);
    uint d0 = cvtpk(s1[12], s1[13]), d1 = cvtpk(s1[14], s1[15]);
    plswap(c0, d0);
    plswap(c1, d1);
    i32x4 w2 = {(int)c0, (int)c1, (int)d0, (int)d1};
    pa[3] = __builtin_bit_cast(bf8, w2);
  }
  __builtin_amdgcn_s_setprio(1);
#pragma unroll
  for (int ks = 0; ks < 4; ++ks) o0 = mfma32(vfA[ks], pa[ks], o0);
#pragma unroll
  for (int ks = 0; ks < 4; ++ks) o1 = mfma32(vfB[ks], pa[ks], o1);
  __builtin_amdgcn_s_setprio(0);
}

__device__ __forceinline__ void tile_out(ushort* ow, const f32x16& o0,
                                         const f32x16& o1, float l, int b,
                                         int h, int qw, int l31, int hi,
                                         int lane, ushort* ao) {
  const float inv = 1.0f / l;
#pragma unroll
  for (int dt = 0; dt < 2; ++dt)
#pragma unroll
    for (int rq = 0; rq < 4; ++rq) {
      const f32x16& ac = dt ? o1 : o0;
      uint2 w;
      w.x = (uint)f2b(ac[rq * 4 + 0] * inv) |
            ((uint)f2b(ac[rq * 4 + 1] * inv) << 16);
      w.y = (uint)f2b(ac[rq * 4 + 2] * inv) |
            ((uint)f2b(ac[rq * 4 + 3] * inv) << 16);
      const int d = dt * 32 + 8 * rq + 4 * hi;
      *(uint2*)&ow[l31 * 66 + d] = w;
    }
  asm volatile("s_waitcnt lgkmcnt(0)" ::: "memory");
  __builtin_amdgcn_sched_barrier(0);
  const int rrow = lane >> 4;
  const int rcol = (lane & 15) * 4;
  const size_t gbase = ((size_t)b * 2048 + qw) * 1024 + h * 64;
#pragma unroll
  for (int i = 0; i < 8; ++i) {
    const int rw = i * 4 + rrow;
    uint2 v = *(const uint2*)&ow[rw * 66 + rcol];
    *(uint2*)&ao[gbase + (size_t)rw * 1024 + rcol] = v;
  }
}

__global__ __launch_bounds__(256) void attn_fwd(const ushort* __restrict__ qh,
                                                const ushort* __restrict__ kh,
                                                const ushort* __restrict__ vT,
                                                ushort* __restrict__ ao) {
  __shared__ ushort kls[2][4096];   // 2 x 8KB K subtiles (swizzled)
  __shared__ ushort vls[2][4096];   // 2 x 8KB V subtiles (swizzled)
  __shared__ ushort olds[4][2176];  // per-wave epilogue transpose scratch
  const int tid = threadIdx.x;
  const int wid = tid >> 6, lane = tid & 63;
  const int l31 = lane & 31, hi = lane >> 5;
  const int gid = blockIdx.x;  // 512
  const int bk = gid & 7;      // b*4 + kv (fixed per XCD -> KV L2-resident)
  const int b = bk >> 2, kv = bk & 3;
  const int rest = gid >> 3;   // 0..63
  const int p = rest & 31, half = rest >> 5;
  const int t = half ? (63 - p) : p;  // pairing: per-CU tile sum = 33
  const int h = kv * 4 + wid;
  const int n = (32 * t + 95) >> 6;   // 64-key tiles: 1..32
  const int nss = (n + 1) >> 1;       // 128-key supersteps: 1..16
  const int qg = t * 32 + l31;

  const ushort* kbase = kh + (size_t)(b * 4 + kv) * 2048 * 64;
  const ushort* vbase = vT + (size_t)(b * 4 + kv) * 64 * 2048;

  // wave w stages chunks {w, w+4} of tile j into buffer half hf
  auto stageTile = [&](int j, int hf) {
    const int k0 = j * 64;
#pragma unroll
    for (int jj2 = 0; jj2 < 2; ++jj2) {
      const int jj = wid + jj2 * 4;
      const int i = jj * 64 + lane;
      const int r = i >> 3, s = i & 7;
      const int sw = (s ^ (r & 7)) << 3;
      gload16(kbase + (size_t)(k0 + r) * 64 + sw, kls[hf] + jj * 512);
      gload16(vbase + (size_t)r * 2048 + k0 + sw, vls[hf] + jj * 512);
    }
  };
  auto stageSS = [&](int ss) {
    const int j0 = 2 * ss;
    const int j1 = (2 * ss + 1 < n) ? (2 * ss + 1) : (n - 1);
    stageTile(j0, 0);
    stageTile(j1, 1);  // duplicate harmless when n odd (never consumed)
  };

  stageSS(0);

  bf8 qf[4];
  {
    const ushort* qb = qh + ((size_t)(b * 16 + h) * 2048 + qg) * 64 + hi * 8;
#pragma unroll
    for (int ks = 0; ks < 4; ++ks) qf[ks] = *(const bf8*)(qb + ks * 16);
  }

  f32x16 o0 = {}, o1 = {};
  float l = 0.f;
  const int sw0 = l31 & 7;

  for (int ss = 0; ss < nss; ++ss) {
    asm volatile("s_waitcnt vmcnt(0)" ::: "memory");  // own loads done
    __builtin_amdgcn_s_barrier();                     // everyone's loads done
    asm volatile("" ::: "memory");
    bf8 kfA[2][4], kfB[2][4], vfA[2][4], vfB[2][4];
#pragma unroll
    for (int hf = 0; hf < 2; ++hf)
#pragma unroll
      for (int ks = 0; ks < 4; ++ks) {
        const int c2 = 2 * ks + hi;
        const int off = (c2 ^ sw0) << 3;
        kfA[hf][ks] = *(const bf8*)&kls[hf][l31 * 64 + off];
        kfB[hf][ks] = *(const bf8*)&kls[hf][(32 + l31) * 64 + off];
        vfA[hf][ks] = *(const bf8*)&vls[hf][l31 * 64 + off];
        vfB[hf][ks] = *(const bf8*)&vls[hf][(32 + l31) * 64 + off];
      }
    asm volatile("s_waitcnt lgkmcnt(0)" ::: "memory");
    __builtin_amdgcn_sched_barrier(0);
    __builtin_amdgcn_s_barrier();  // all reads drained -> safe overwrite
    if (ss + 1 < nss) stageSS(ss + 1);
    const int j0 = 2 * ss, j1 = 2 * ss + 1;
    astep2(kfA[0], kfB[0], vfA[0], vfB[0], qf, o0, o1, l, j0 * 64, qg,
           j0 == n - 1, hi);
    if (j1 < n)
      astep2(kfA[1], kfB[1], vfA[1], vfB[1], qf, o0, o1, l, j1 * 64, qg,
             j1 == n - 1, hi);
  }
  tile_out(olds[wid], o0, o1, l, b, h, t * 32, l31, hi, lane, ao);
}

extern "C" void kernel_launch(void* const* d_in, const int* in_sizes, int n_in,
                              void* d_out, int out_size, void* d_ws,
                              size_t ws_size, hipStream_t stream) {
  (void)in_sizes; (void)n_in; (void)out_size; (void)ws_size;
  const float* x = (const float*)d_in[0];
  const float* wq = (const float*)d_in[1];
  const float* wk = (const float*)d_in[2];
  const float* wv = (const float*)d_in[3];
  const float* wo = (const float*)d_in[4];
  const float* fc = (const float*)d_in[5];
  const float* fs = (const float*)d_in[6];
  float* out = (float*)d_out;

  ushort* xb = (ushort*)d_ws;               // 4096x1024
  ushort* wqkvT = xb + 4194304;             // 1536x1024
  ushort* woT = wqkvT + 1572864;            // 1024x1024
  ushort* qkv = woT + 1048576;              // 4096x1536
  ushort* qh = qkv + 6291456;               // 32x2048x64
  ushort* kh = qh + 4194304;                // 8x2048x64
  ushort* vTb = kh + 1048576;               // 8x64x2048
  ushort* ao = vTb + 1048576;               // 4096x1024

  prep1<<<6656, 256, 0, stream>>>(x, wq, wk, wv, wo, xb, wqkvT, woT);
  gemm_bt<true><<<768, 256, 0, stream>>>(xb, wqkvT, qkv, 4096, 1536, 1024, 12);
  prep2<<<10496, 256, 0, stream>>>(qkv, fc, fs, qh, kh, vTb);
  attn_fwd<<<512, 256, 0, stream>>>(qh, kh, vTb, ao);
  gemm_bt<false><<<512, 256, 0, stream>>>(ao, woT, out, 4096, 1024, 1024, 8);
}

// Round 20
// 102.633 us; speedup vs baseline: 1.0684x; 1.0304x over previous
//
#include <hip/hip_runtime.h>

typedef short bf8 __attribute__((ext_vector_type(8)));   // 8 bf16 in 4 VGPRs
typedef float f32x4 __attribute__((ext_vector_type(4)));
typedef float f32x16 __attribute__((ext_vector_type(16)));
typedef int i32x4 __attribute__((ext_vector_type(4)));

__device__ __forceinline__ ushort f2b(float f) {
  unsigned x = __builtin_bit_cast(unsigned, f);
  unsigned r = (x + 0x7fffu + ((x >> 16) & 1u)) >> 16;
  return (ushort)r;
}
__device__ __forceinline__ float b2f(ushort u) {
  unsigned x = ((unsigned)u) << 16;
  return __builtin_bit_cast(float, x);
}

__device__ __forceinline__ f32x4 mfma16(bf8 a, bf8 b, f32x4 c) {
  return __builtin_amdgcn_mfma_f32_16x16x32_bf16(a, b, c, 0, 0, 0);
}
__device__ __forceinline__ f32x16 mfma32(bf8 a, bf8 b, f32x16 c) {
  return __builtin_amdgcn_mfma_f32_32x32x16_bf16(a, b, c, 0, 0, 0);
}

__device__ __forceinline__ float fexp2(float x) {
#if __has_builtin(__builtin_amdgcn_exp2f)
  return __builtin_amdgcn_exp2f(x);
#else
  return exp2f(x);
#endif
}

__device__ __forceinline__ uint cvtpk(float lo, float hi_) {
  uint r;
  asm("v_cvt_pk_bf16_f32 %0, %1, %2" : "=v"(r) : "v"(lo), "v"(hi_));
  return r;
}
__device__ __forceinline__ void plswap(uint& a, uint& b) {
  asm("v_permlane32_swap_b32 %0, %1" : "+v"(a), "+v"(b));
}

__device__ __forceinline__ void gload16(const ushort* g, ushort* l) {
  __builtin_amdgcn_global_load_lds(
      (const __attribute__((address_space(1))) void*)g,
      (__attribute__((address_space(3))) void*)l, 16, 0, 0);
}

// ---------------- prep1: cast x (f32->bf16) + all weight transposes ------
__global__ __launch_bounds__(256) void prep1(
    const float* __restrict__ x, const float* __restrict__ wq,
    const float* __restrict__ wk, const float* __restrict__ wv,
    const float* __restrict__ wo, ushort* __restrict__ xb,
    ushort* __restrict__ wqkvT, ushort* __restrict__ woT) {
  __shared__ float tile[32][33];
  const int bid = blockIdx.x;
  if (bid < 4096) {
    const int i = (bid * 256 + threadIdx.x) * 4;
    float4 v = *(const float4*)(x + i);
    ushort4 o;
    o.x = f2b(v.x); o.y = f2b(v.y); o.z = f2b(v.z); o.w = f2b(v.w);
    *(ushort4*)(xb + i) = o;
    return;
  }
  int t = bid - 4096;  // 0..2559
  const float* src;
  ushort* dst;
  int N;
  if (t < 1024) {
    src = wq; dst = wqkvT; N = 1024;
  } else if (t < 1280) {
    src = wk; dst = wqkvT + 1024 * 1024; N = 256; t -= 1024;
  } else if (t < 1536) {
    src = wv; dst = wqkvT + 1280 * 1024; N = 256; t -= 1280;
  } else {
    src = wo; dst = woT; N = 1024; t -= 1536;
  }
  const int kx = (t & 31) * 32, nx = (t >> 5) * 32;
  const int tx = threadIdx.x & 31, ty = threadIdx.x >> 5;
#pragma unroll
  for (int i = ty; i < 32; i += 8)
    tile[i][tx] = src[(size_t)(kx + i) * N + nx + tx];
  __syncthreads();
#pragma unroll
  for (int i = ty; i < 32; i += 8)
    dst[(size_t)(nx + i) * 1024 + kx + tx] = f2b(tile[tx][i]);
}

// ------- GEMM C[M][N]=A[M][K]*Bt[N][K]^T; 64x128, BK=64, double-buffered --
// XCD-swizzled 1D grid. Per iter: vmcnt(0) [own stage(it), issued a full
// compute phase earlier, lands ~free] -> s_barrier [stage(it) landed AND
// iter it-1 reads drained] -> stage(it+1) into other parity [overwrites
// parity it-1, safe] -> frag reads parity it -> lgkm(0) -> 16 MFMAs.
// Raw s_barrier (not __syncthreads) keeps the staging queue alive across
// the barrier. LDS 48KB: gemm1 768 blocks = 3/CU (144KB), gemm2 512 = 2/CU.
template <bool OUT_BF16>
__global__ __launch_bounds__(256) void gemm_bt(const ushort* __restrict__ A,
                                               const ushort* __restrict__ Bt,
                                               void* __restrict__ Cv, int M,
                                               int N, int K, int nbx) {
  __shared__ ushort aL[2][64 * 64];    // 2 x 8 KB
  __shared__ ushort bL[2][128 * 64];   // 2 x 16 KB
  const int tid = threadIdx.x;
  const int wid = tid >> 6, lane = tid & 63;
  const int l15 = lane & 15, l4 = lane >> 4;
  const int qch = gridDim.x >> 3;
  const int sw = (blockIdx.x & 7) * qch + (blockIdx.x >> 3);
  const int bxi = sw % nbx, byi = sw / nbx;
  const int bm = byi * 64, bn = bxi * 128;
  const int wr = (wid & 1) * 32, wc = (wid >> 1) * 64;
  const int nIter = K >> 6;

  auto stage = [&](int it, int par) {
    const int kb = it * 64;
#pragma unroll
    for (int i = 0; i < 2; ++i) {  // A: 64x64 = 512 chunks, 2/thread
      const int e = (i * 256 + tid) * 8;
      const int r = e >> 6, c = e & 63;
      gload16(A + (size_t)(bm + r) * K + kb + c,
              &aL[par][i * 2048 + wid * 512]);
    }
#pragma unroll
    for (int i = 0; i < 4; ++i) {  // B: 128x64 = 1024 chunks, 4/thread
      const int e = (i * 256 + tid) * 8;
      const int r = e >> 6, c = e & 63;
      gload16(Bt + (size_t)(bn + r) * K + kb + c,
              &bL[par][i * 2048 + wid * 512]);
    }
  };

  stage(0, 0);
  f32x4 acc[2][4] = {};
  for (int it = 0; it < nIter; ++it) {
    const int par = it & 1;
    asm volatile("s_waitcnt vmcnt(0)" ::: "memory");  // own stage(it) landed
    __builtin_amdgcn_s_barrier();  // collective: stage(it) landed; it-1 reads
                                   // drained -> parity it+1 (==it-1) free
    asm volatile("" ::: "memory");
    if (it + 1 < nIter) stage(it + 1, par ^ 1);
    bf8 af[2][2], bfr[4][2];
#pragma unroll
    for (int i = 0; i < 2; ++i)
#pragma unroll
      for (int kk = 0; kk < 2; ++kk)
        af[i][kk] =
            *(const bf8*)&aL[par][(wr + i * 16 + l15) * 64 + kk * 32 + l4 * 8];
#pragma unroll
    for (int j = 0; j < 4; ++j)
#pragma unroll
      for (int kk = 0; kk < 2; ++kk)
        bfr[j][kk] =
            *(const bf8*)&bL[par][(wc + j * 16 + l15) * 64 + kk * 32 + l4 * 8];
    asm volatile("s_waitcnt lgkmcnt(0)" ::: "memory");
    __builtin_amdgcn_sched_barrier(0);
#pragma unroll
    for (int kk = 0; kk < 2; ++kk)
#pragma unroll
      for (int i = 0; i < 2; ++i)
#pragma unroll
        for (int j = 0; j < 4; ++j)
          acc[i][j] = mfma16(af[i][kk], bfr[j][kk], acc[i][j]);
  }
#pragma unroll
  for (int i = 0; i < 2; ++i)
#pragma unroll
    for (int j = 0; j < 4; ++j)
#pragma unroll
      for (int r = 0; r < 4; ++r) {
        const size_t row = bm + wr + i * 16 + l4 * 4 + r;
        const size_t col = bn + wc + j * 16 + l15;
        if constexpr (OUT_BF16)
          ((ushort*)Cv)[row * N + col] = f2b(acc[i][j][r]);
        else
          ((float*)Cv)[row * N + col] = acc[i][j][r];
      }
}

// ---------------- prep2: RoPE for Q,K + V transpose ----------------
// Q is pre-scaled by 0.125*log2(e) so attention scores are in log2 domain.
__global__ __launch_bounds__(256) void prep2(const ushort* __restrict__ qkv,
                                             const float* __restrict__ fc,
                                             const float* __restrict__ fs,
                                             ushort* __restrict__ qh,
                                             ushort* __restrict__ kh,
                                             ushort* __restrict__ vT) {
  __shared__ ushort tile[64][65];
  if (blockIdx.x < 10240) {
    const int idx = blockIdx.x * 256 + threadIdx.x;  // 4096*640 total
    const int u = idx % 640;
    const int m = idx / 640;
    const int s = m & 2047, b = m >> 11;
    int col, j;
    if (u < 512) {
      j = u & 31;
      col = (u >> 5) * 64 + 2 * j;
    } else {
      j = (u - 512) & 31;
      col = 1024 + ((u - 512) >> 5) * 64 + 2 * j;
    }
    const uint pr = *(const uint*)(qkv + (size_t)m * 1536 + col);
    const float tr = b2f((ushort)(pr & 0xffff));
    const float ti = b2f((ushort)(pr >> 16));
    const float c = fc[s * 32 + j], sn = fs[s * 32 + j];
    float orr = tr * c - ti * sn;
    float oi = tr * sn + ti * c;
    if (u < 512) {
      orr *= 0.18033688f;  // (1/sqrt(64)) * log2(e)
      oi *= 0.18033688f;
      const uint w = (uint)f2b(orr) | ((uint)f2b(oi) << 16);
      *(uint*)(qh + ((size_t)(b * 16 + (u >> 5)) * 2048 + s) * 64 + 2 * j) = w;
    } else {
      const uint w = (uint)f2b(orr) | ((uint)f2b(oi) << 16);
      const int kv = (u - 512) >> 5;
      *(uint*)(kh + ((size_t)(b * 4 + kv) * 2048 + s) * 64 + 2 * j) = w;
    }
    return;
  }
  // V transpose: 256 blocks
  const int id = blockIdx.x - 10240;
  const int st = id & 31, kv = (id >> 5) & 3, b = id >> 7;
  const int tid = threadIdx.x;
  for (int e = tid; e < 4096; e += 256) {
    const int r = e >> 6, c = e & 63;
    tile[r][c] =
        qkv[(size_t)(b * 2048 + st * 64 + r) * 1536 + 1280 + kv * 64 + c];
  }
  __syncthreads();
  for (int e = tid; e < 4096; e += 256) {
    const int d = e >> 6, c = e & 63;
    vT[((size_t)(b * 4 + kv) * 64 + d) * 2048 + st * 64 + c] = tile[c][d];
  }
}

// ---------------- Flash attention v11 (R17 best): 128-key supersteps ------
// 512 blocks x 256 thr (4 waves = 4 heads of one kv group, shared KV stage).
// Pairing t = half ? 63-p : p (per-CU work sum = 33 tiles). Superstep = 2
// 64-key subtiles per barrier pair: stage 32KB (8 gloads/wave, uniform),
// vmcnt+barrier, read BOTH subtiles' frags, lgkm+barrier, stage next
// superstep, then two astep2 calls. Fixed-max softmax (log2 domain).

#define MCONST 12.0f

__device__ __forceinline__ void astep2(const bf8 (&kfA)[4], const bf8 (&kfB)[4],
                                       const bf8 (&vfA)[4], const bf8 (&vfB)[4],
                                       const bf8 (&qf)[4], f32x16& o0,
                                       f32x16& o1, float& l, int k0, int qg,
                                       bool maskt, int hi) {
  f32x16 s0 = {}, s1 = {};
  __builtin_amdgcn_s_setprio(1);
#pragma unroll
  for (int ks = 0; ks < 4; ++ks) s0 = mfma32(kfA[ks], qf[ks], s0);
#pragma unroll
  for (int ks = 0; ks < 4; ++ks) s1 = mfma32(kfB[ks], qf[ks], s1);
  __builtin_amdgcn_s_setprio(0);
  if (maskt) {
#pragma unroll
    for (int r = 0; r < 16; ++r) {
      const int key = k0 + (r & 3) + 8 * (r >> 2) + 4 * hi;
      if (key > qg) s0[r] = -1e30f;
      if (key + 32 > qg) s1[r] = -1e30f;
    }
  }
  float t[16];
#pragma unroll
  for (int r = 0; r < 16; ++r) {
    s0[r] = fexp2(s0[r] - MCONST);
    s1[r] = fexp2(s1[r] - MCONST);
    t[r] = s0[r] + s1[r];
  }
#pragma unroll
  for (int st = 8; st > 0; st >>= 1)
#pragma unroll
    for (int r = 0; r < st; ++r) t[r] += t[r + st];
  l += t[0] + __shfl_xor(t[0], 32);
  bf8 pa[4];
  {
    uint a0 = cvtpk(s0[0], s0[1]), a1 = cvtpk(s0[2], s0[3]);
    uint b0 = cvtpk(s0[4], s0[5]), b1 = cvtpk(s0[6], s0[7]);
    plswap(a0, b0);
    plswap(a1, b1);
    i32x4 w = {(int)a0, (int)a1, (int)b0, (int)b1};
    pa[0] = __builtin_bit_cast(bf8, w);
    uint c0 = cvtpk(s0[8], s0[9]), c1 = cvtpk(s0[10], s0[11]);
    uint d0 = cvtpk(s0[12], s0[13]), d1 = cvtpk(s0[14], s0[15]);
    plswap(c0, d0);
    plswap(c1, d1);
    i32x4 w2 = {(int)c0, (int)c1, (int)d0, (int)d1};
    pa[1] = __builtin_bit_cast(bf8, w2);
  }
  {
    uint a0 = cvtpk(s1[0], s1[1]), a1 = cvtpk(s1[2], s1[3]);
    uint b0 = cvtpk(s1[4], s1[5]), b1 = cvtpk(s1[6], s1[7]);
    plswap(a0, b0);
    plswap(a1, b1);
    i32x4 w = {(int)a0, (int)a1, (int)b0, (int)b1};
    pa[2] = __builtin_bit_cast(bf8, w);
    uint c0 = cvtpk(s1[8], s1[9]), c1 = cvtpk(s1[10], s1[11]);
    uint d0 = cvtpk(s1[12], s1[13]), d1 = cvtpk(s1[14], s1[15]);
    plswap(c0, d0);
    plswap(c1, d1);
    i32x4 w2 = {(int)c0, (int)c1, (int)d0, (int)d1};
    pa[3] = __builtin_bit_cast(bf8, w2);
  }
  __builtin_amdgcn_s_setprio(1);
#pragma unroll
  for (int ks = 0; ks < 4; ++ks) o0 = mfma32(vfA[ks], pa[ks], o0);
#pragma unroll
  for (int ks = 0; ks < 4; ++ks) o1 = mfma32(vfB[ks], pa[ks], o1);
  __builtin_amdgcn_s_setprio(0);
}

__device__ __forceinline__ void tile_out(ushort* ow, const f32x16& o0,
                                         const f32x16& o1, float l, int b,
                                         int h, int qw, int l31, int hi,
                                         int lane, ushort* ao) {
  const float inv = 1.0f / l;
#pragma unroll
  for (int dt = 0; dt < 2; ++dt)
#pragma unroll
    for (int rq = 0; rq < 4; ++rq) {
      const f32x16& ac = dt ? o1 : o0;
      uint2 w;
      w.x = (uint)f2b(ac[rq * 4 + 0] * inv) |
            ((uint)f2b(ac[rq * 4 + 1] * inv) << 16);
      w.y = (uint)f2b(ac[rq * 4 + 2] * inv) |
            ((uint)f2b(ac[rq * 4 + 3] * inv) << 16);
      const int d = dt * 32 + 8 * rq + 4 * hi;
      *(uint2*)&ow[l31 * 66 + d] = w;
    }
  asm volatile("s_waitcnt lgkmcnt(0)" ::: "memory");
  __builtin_amdgcn_sched_barrier(0);
  const int rrow = lane >> 4;
  const int rcol = (lane & 15) * 4;
  const size_t gbase = ((size_t)b * 2048 + qw) * 1024 + h * 64;
#pragma unroll
  for (int i = 0; i < 8; ++i) {
    const int rw = i * 4 + rrow;
    uint2 v = *(const uint2*)&ow[rw * 66 + rcol];
    *(uint2*)&ao[gbase + (size_t)rw * 1024 + rcol] = v;
  }
}

__global__ __launch_bounds__(256) void attn_fwd(const ushort* __restrict__ qh,
                                                const ushort* __restrict__ kh,
                                                const ushort* __restrict__ vT,
                                                ushort* __restrict__ ao) {
  __shared__ ushort kls[2][4096];   // 2 x 8KB K subtiles (swizzled)
  __shared__ ushort vls[2][4096];   // 2 x 8KB V subtiles (swizzled)
  __shared__ ushort olds[4][2176];  // per-wave epilogue transpose scratch
  const int tid = threadIdx.x;
  const int wid = tid >> 6, lane = tid & 63;
  const int l31 = lane & 31, hi = lane >> 5;
  const int gid = blockIdx.x;  // 512
  const int bk = gid & 7;      // b*4 + kv (fixed per XCD -> KV L2-resident)
  const int b = bk >> 2, kv = bk & 3;
  const int rest = gid >> 3;   // 0..63
  const int p = rest & 31, half = rest >> 5;
  const int t = half ? (63 - p) : p;  // pairing: per-CU tile sum = 33
  const int h = kv * 4 + wid;
  const int n = (32 * t + 95) >> 6;   // 64-key tiles: 1..32
  const int nss = (n + 1) >> 1;       // 128-key supersteps: 1..16
  const int qg = t * 32 + l31;

  const ushort* kbase = kh + (size_t)(b * 4 + kv) * 2048 * 64;
  const ushort* vbase = vT + (size_t)(b * 4 + kv) * 64 * 2048;

  // wave w stages chunks {w, w+4} of tile j into buffer half hf
  auto stageTile = [&](int j, int hf) {
    const int k0 = j * 64;
#pragma unroll
    for (int jj2 = 0; jj2 < 2; ++jj2) {
      const int jj = wid + jj2 * 4;
      const int i = jj * 64 + lane;
      const int r = i >> 3, s = i & 7;
      const int sw = (s ^ (r & 7)) << 3;
      gload16(kbase + (size_t)(k0 + r) * 64 + sw, kls[hf] + jj * 512);
      gload16(vbase + (size_t)r * 2048 + k0 + sw, vls[hf] + jj * 512);
    }
  };
  auto stageSS = [&](int ss) {
    const int j0 = 2 * ss;
    const int j1 = (2 * ss + 1 < n) ? (2 * ss + 1) : (n - 1);
    stageTile(j0, 0);
    stageTile(j1, 1);  // duplicate harmless when n odd (never consumed)
  };

  stageSS(0);

  bf8 qf[4];
  {
    const ushort* qb = qh + ((size_t)(b * 16 + h) * 2048 + qg) * 64 + hi * 8;
#pragma unroll
    for (int ks = 0; ks < 4; ++ks) qf[ks] = *(const bf8*)(qb + ks * 16);
  }

  f32x16 o0 = {}, o1 = {};
  float l = 0.f;
  const int sw0 = l31 & 7;

  for (int ss = 0; ss < nss; ++ss) {
    asm volatile("s_waitcnt vmcnt(0)" ::: "memory");  // own loads done
    __builtin_amdgcn_s_barrier();                     // everyone's loads done
    asm volatile("" ::: "memory");
    bf8 kfA[2][4], kfB[2][4], vfA[2][4], vfB[2][4];
#pragma unroll
    for (int hf = 0; hf < 2; ++hf)
#pragma unroll
      for (int ks = 0; ks < 4; ++ks) {
        const int c2 = 2 * ks + hi;
        const int off = (c2 ^ sw0) << 3;
        kfA[hf][ks] = *(const bf8*)&kls[hf][l31 * 64 + off];
        kfB[hf][ks] = *(const bf8*)&kls[hf][(32 + l31) * 64 + off];
        vfA[hf][ks] = *(const bf8*)&vls[hf][l31 * 64 + off];
        vfB[hf][ks] = *(const bf8*)&vls[hf][(32 + l31) * 64 + off];
      }
    asm volatile("s_waitcnt lgkmcnt(0)" ::: "memory");
    __builtin_amdgcn_sched_barrier(0);
    __builtin_amdgcn_s_barrier();  // all reads drained -> safe overwrite
    if (ss + 1 < nss) stageSS(ss + 1);
    const int j0 = 2 * ss, j1 = 2 * ss + 1;
    astep2(kfA[0], kfB[0], vfA[0], vfB[0], qf, o0, o1, l, j0 * 64, qg,
           j0 == n - 1, hi);
    if (j1 < n)
      astep2(kfA[1], kfB[1], vfA[1], vfB[1], qf, o0, o1, l, j1 * 64, qg,
             j1 == n - 1, hi);
  }
  tile_out(olds[wid], o0, o1, l, b, h, t * 32, l31, hi, lane, ao);
}

extern "C" void kernel_launch(void* const* d_in, const int* in_sizes, int n_in,
                              void* d_out, int out_size, void* d_ws,
                              size_t ws_size, hipStream_t stream) {
  (void)in_sizes; (void)n_in; (void)out_size; (void)ws_size;
  const float* x = (const float*)d_in[0];
  const float* wq = (const float*)d_in[1];
  const float* wk = (const float*)d_in[2];
  const float* wv = (const float*)d_in[3];
  const float* wo = (const float*)d_in[4];
  const float* fc = (const float*)d_in[5];
  const float* fs = (const float*)d_in[6];
  float* out = (float*)d_out;

  ushort* xb = (ushort*)d_ws;               // 4096x1024
  ushort* wqkvT = xb + 4194304;             // 1536x1024
  ushort* woT = wqkvT + 1572864;            // 1024x1024
  ushort* qkv = woT + 1048576;              // 4096x1536
  ushort* qh = qkv + 6291456;               // 32x2048x64
  ushort* kh = qh + 4194304;                // 8x2048x64
  ushort* vTb = kh + 1048576;               // 8x64x2048
  ushort* ao = vTb + 1048576;               // 4096x1024

  prep1<<<6656, 256, 0, stream>>>(x, wq, wk, wv, wo, xb, wqkvT, woT);
  gemm_bt<true><<<768, 256, 0, stream>>>(xb, wqkvT, qkv, 4096, 1536, 1024, 12);
  prep2<<<10496, 256, 0, stream>>>(qkv, fc, fs, qh, kh, vTb);
  attn_fwd<<<512, 256, 0, stream>>>(qh, kh, vTb, ao);
  gemm_bt<false><<<512, 256, 0, stream>>>(ao, woT, out, 4096, 1024, 1024, 8);
}

// Round 21
// 98.005 us; speedup vs baseline: 1.1189x; 1.0472x over previous
//
#include <hip/hip_runtime.h>

typedef short bf8 __attribute__((ext_vector_type(8)));   // 8 bf16 in 4 VGPRs
typedef float f32x4 __attribute__((ext_vector_type(4)));
typedef float f32x16 __attribute__((ext_vector_type(16)));
typedef int i32x4 __attribute__((ext_vector_type(4)));

__device__ __forceinline__ ushort f2b(float f) {
  unsigned x = __builtin_bit_cast(unsigned, f);
  unsigned r = (x + 0x7fffu + ((x >> 16) & 1u)) >> 16;
  return (ushort)r;
}
__device__ __forceinline__ float b2f(ushort u) {
  unsigned x = ((unsigned)u) << 16;
  return __builtin_bit_cast(float, x);
}

__device__ __forceinline__ f32x4 mfma16(bf8 a, bf8 b, f32x4 c) {
  return __builtin_amdgcn_mfma_f32_16x16x32_bf16(a, b, c, 0, 0, 0);
}
__device__ __forceinline__ f32x16 mfma32(bf8 a, bf8 b, f32x16 c) {
  return __builtin_amdgcn_mfma_f32_32x32x16_bf16(a, b, c, 0, 0, 0);
}

__device__ __forceinline__ float fexp2(float x) {
#if __has_builtin(__builtin_amdgcn_exp2f)
  return __builtin_amdgcn_exp2f(x);
#else
  return exp2f(x);
#endif
}

__device__ __forceinline__ uint cvtpk(float lo, float hi_) {
  uint r;
  asm("v_cvt_pk_bf16_f32 %0, %1, %2" : "=v"(r) : "v"(lo), "v"(hi_));
  return r;
}
__device__ __forceinline__ void plswap(uint& a, uint& b) {
  asm("v_permlane32_swap_b32 %0, %1" : "+v"(a), "+v"(b));
}

__device__ __forceinline__ void gload16(const ushort* g, ushort* l) {
  __builtin_amdgcn_global_load_lds(
      (const __attribute__((address_space(1))) void*)g,
      (__attribute__((address_space(3))) void*)l, 16, 0, 0);
}

// ---------------- prep1: cast x (f32->bf16) + all weight transposes ------
__global__ __launch_bounds__(256) void prep1(
    const float* __restrict__ x, const float* __restrict__ wq,
    const float* __restrict__ wk, const float* __restrict__ wv,
    const float* __restrict__ wo, ushort* __restrict__ xb,
    ushort* __restrict__ wqkvT, ushort* __restrict__ woT) {
  __shared__ float tile[32][33];
  const int bid = blockIdx.x;
  if (bid < 4096) {
    const int i = (bid * 256 + threadIdx.x) * 4;
    float4 v = *(const float4*)(x + i);
    ushort4 o;
    o.x = f2b(v.x); o.y = f2b(v.y); o.z = f2b(v.z); o.w = f2b(v.w);
    *(ushort4*)(xb + i) = o;
    return;
  }
  int t = bid - 4096;  // 0..2559
  const float* src;
  ushort* dst;
  int N;
  if (t < 1024) {
    src = wq; dst = wqkvT; N = 1024;
  } else if (t < 1280) {
    src = wk; dst = wqkvT + 1024 * 1024; N = 256; t -= 1024;
  } else if (t < 1536) {
    src = wv; dst = wqkvT + 1280 * 1024; N = 256; t -= 1280;
  } else {
    src = wo; dst = woT; N = 1024; t -= 1536;
  }
  const int kx = (t & 31) * 32, nx = (t >> 5) * 32;
  const int tx = threadIdx.x & 31, ty = threadIdx.x >> 5;
#pragma unroll
  for (int i = ty; i < 32; i += 8)
    tile[i][tx] = src[(size_t)(kx + i) * N + nx + tx];
  __syncthreads();
#pragma unroll
  for (int i = ty; i < 32; i += 8)
    dst[(size_t)(nx + i) * 1024 + kx + tx] = f2b(tile[tx][i]);
}

// ------- gemm_rope: x @ wqkvT with FUSED RoPE + V-transpose epilogue ------
// 64x128 tile, BK=64, double-buffered, XCD-swizzled (768 blocks, nbx=12).
// bxi<8: Q cols -> RoPE (scaled 0.125*log2e) -> qh.  bxi 8,9: K -> RoPE ->
// kh.  bxi 10,11: V -> LDS transpose -> vT. RoPE pair (2j,2j+1) lives in
// adjacent lanes (l15 parity == d parity): one shfl_xor(val,1) provides the
// partner element; computed on pre-rounding f32 acc.
__global__ __launch_bounds__(256) void gemm_rope(
    const ushort* __restrict__ A, const ushort* __restrict__ Bt,
    const float* __restrict__ fc, const float* __restrict__ fs,
    ushort* __restrict__ qh, ushort* __restrict__ kh,
    ushort* __restrict__ vT) {
  __shared__ ushort aL[2][64 * 64];    // 2 x 8 KB
  __shared__ ushort bL[2][128 * 64];   // 2 x 16 KB (reused for V transpose)
  const int K = 1024;
  const int tid = threadIdx.x;
  const int wid = tid >> 6, lane = tid & 63;
  const int l15 = lane & 15, l4 = lane >> 4;
  const int qch = gridDim.x >> 3;
  const int sw = (blockIdx.x & 7) * qch + (blockIdx.x >> 3);
  const int bxi = sw % 12, byi = sw / 12;
  const int bm = byi * 64, bn = bxi * 128;
  const int wr = (wid & 1) * 32, wc = (wid >> 1) * 64;
  const int nIter = K >> 6;

  auto stage = [&](int it, int par) {
    const int kb = it * 64;
#pragma unroll
    for (int i = 0; i < 2; ++i) {
      const int e = (i * 256 + tid) * 8;
      const int r = e >> 6, c = e & 63;
      gload16(A + (size_t)(bm + r) * K + kb + c,
              &aL[par][i * 2048 + wid * 512]);
    }
#pragma unroll
    for (int i = 0; i < 4; ++i) {
      const int e = (i * 256 + tid) * 8;
      const int r = e >> 6, c = e & 63;
      gload16(Bt + (size_t)(bn + r) * K + kb + c,
              &bL[par][i * 2048 + wid * 512]);
    }
  };

  stage(0, 0);
  f32x4 acc[2][4] = {};
  for (int it = 0; it < nIter; ++it) {
    const int par = it & 1;
    asm volatile("s_waitcnt vmcnt(0)" ::: "memory");
    __builtin_amdgcn_s_barrier();
    asm volatile("" ::: "memory");
    if (it + 1 < nIter) stage(it + 1, par ^ 1);
    bf8 af[2][2], bfr[4][2];
#pragma unroll
    for (int i = 0; i < 2; ++i)
#pragma unroll
      for (int kk = 0; kk < 2; ++kk)
        af[i][kk] =
            *(const bf8*)&aL[par][(wr + i * 16 + l15) * 64 + kk * 32 + l4 * 8];
#pragma unroll
    for (int j = 0; j < 4; ++j)
#pragma unroll
      for (int kk = 0; kk < 2; ++kk)
        bfr[j][kk] =
            *(const bf8*)&bL[par][(wc + j * 16 + l15) * 64 + kk * 32 + l4 * 8];
    asm volatile("s_waitcnt lgkmcnt(0)" ::: "memory");
    __builtin_amdgcn_sched_barrier(0);
#pragma unroll
    for (int kk = 0; kk < 2; ++kk)
#pragma unroll
      for (int i = 0; i < 2; ++i)
#pragma unroll
        for (int j = 0; j < 4; ++j)
          acc[i][j] = mfma16(af[i][kk], bfr[j][kk], acc[i][j]);
  }

  if (bxi < 10) {
    // ---- Q or K: fused RoPE, direct write ----
    const bool isQ = bxi < 8;
    const float qs = isQ ? 0.18033688f : 1.0f;  // (1/8)*log2(e) for Q
    const int colbase = bn + wc;
    const int head = isQ ? (colbase >> 6) : ((colbase - 1024) >> 6);
    const int nh = isQ ? 16 : 4;
    ushort* outp = isQ ? qh : kh;
#pragma unroll
    for (int i = 0; i < 2; ++i)
#pragma unroll
      for (int j = 0; j < 4; ++j) {
        const int d = j * 16 + l15;
        const int d2 = d >> 1;
#pragma unroll
        for (int r = 0; r < 4; ++r) {
          const int row = bm + wr + i * 16 + l4 * 4 + r;
          const int s = row & 2047, bb = row >> 11;
          const float c = fc[s * 32 + d2], sn = fs[s * 32 + d2];
          const float val = acc[i][j][r];
          const float par = __shfl_xor(val, 1);
          float o;
          if ((l15 & 1) == 0)
            o = (val * c - par * sn) * qs;  // even d: tr*c - ti*s
          else
            o = (par * sn + val * c) * qs;  // odd d: tr*s + ti*c
          outp[((size_t)(bb * nh + head) * 2048 + s) * 64 + d] = f2b(o);
        }
      }
  } else {
    // ---- V: LDS transpose (reuse bL, free after K-loop) then write vT ----
    __syncthreads();  // block-uniform branch; all frag reads already in regs
    ushort* ldsT = &bL[0][0];  // 128 x 68 ushorts = 17 KB <= 32 KB
#pragma unroll
    for (int i = 0; i < 2; ++i)
#pragma unroll
      for (int j = 0; j < 4; ++j) {
        const int cl = wc + j * 16 + l15;
#pragma unroll
        for (int r = 0; r < 4; ++r) {
          const int rl = wr + i * 16 + l4 * 4 + r;
          ldsT[cl * 68 + rl] = f2b(acc[i][j][r]);
        }
      }
    __syncthreads();
    const int bb = bm >> 11, sbase = bm & 2047;
    const int dl = tid >> 1, sh = (tid & 1) * 32;
    const int gcol = bn + dl - 1280;
    const int kv = gcol >> 6, d = gcol & 63;
    ushort* dst = vT + ((size_t)(bb * 4 + kv) * 64 + d) * 2048 + sbase + sh;
    const ushort* srcl = ldsT + dl * 68 + sh;
#pragma unroll
    for (int k = 0; k < 8; ++k)
      *(uint2*)(dst + k * 4) = *(const uint2*)(srcl + k * 4);
  }
}

// ------- GEMM C[M][N]=A[M][K]*Bt[N][K]^T; 64x128, BK=64, double-buffered --
template <bool OUT_BF16>
__global__ __launch_bounds__(256) void gemm_bt(const ushort* __restrict__ A,
                                               const ushort* __restrict__ Bt,
                                               void* __restrict__ Cv, int M,
                                               int N, int K, int nbx) {
  __shared__ ushort aL[2][64 * 64];    // 2 x 8 KB
  __shared__ ushort bL[2][128 * 64];   // 2 x 16 KB
  const int tid = threadIdx.x;
  const int wid = tid >> 6, lane = tid & 63;
  const int l15 = lane & 15, l4 = lane >> 4;
  const int qch = gridDim.x >> 3;
  const int sw = (blockIdx.x & 7) * qch + (blockIdx.x >> 3);
  const int bxi = sw % nbx, byi = sw / nbx;
  const int bm = byi * 64, bn = bxi * 128;
  const int wr = (wid & 1) * 32, wc = (wid >> 1) * 64;
  const int nIter = K >> 6;

  auto stage = [&](int it, int par) {
    const int kb = it * 64;
#pragma unroll
    for (int i = 0; i < 2; ++i) {
      const int e = (i * 256 + tid) * 8;
      const int r = e >> 6, c = e & 63;
      gload16(A + (size_t)(bm + r) * K + kb + c,
              &aL[par][i * 2048 + wid * 512]);
    }
#pragma unroll
    for (int i = 0; i < 4; ++i) {
      const int e = (i * 256 + tid) * 8;
      const int r = e >> 6, c = e & 63;
      gload16(Bt + (size_t)(bn + r) * K + kb + c,
              &bL[par][i * 2048 + wid * 512]);
    }
  };

  stage(0, 0);
  f32x4 acc[2][4] = {};
  for (int it = 0; it < nIter; ++it) {
    const int par = it & 1;
    asm volatile("s_waitcnt vmcnt(0)" ::: "memory");
    __builtin_amdgcn_s_barrier();
    asm volatile("" ::: "memory");
    if (it + 1 < nIter) stage(it + 1, par ^ 1);
    bf8 af[2][2], bfr[4][2];
#pragma unroll
    for (int i = 0; i < 2; ++i)
#pragma unroll
      for (int kk = 0; kk < 2; ++kk)
        af[i][kk] =
            *(const bf8*)&aL[par][(wr + i * 16 + l15) * 64 + kk * 32 + l4 * 8];
#pragma unroll
    for (int j = 0; j < 4; ++j)
#pragma unroll
      for (int kk = 0; kk < 2; ++kk)
        bfr[j][kk] =
            *(const bf8*)&bL[par][(wc + j * 16 + l15) * 64 + kk * 32 + l4 * 8];
    asm volatile("s_waitcnt lgkmcnt(0)" ::: "memory");
    __builtin_amdgcn_sched_barrier(0);
#pragma unroll
    for (int kk = 0; kk < 2; ++kk)
#pragma unroll
      for (int i = 0; i < 2; ++i)
#pragma unroll
        for (int j = 0; j < 4; ++j)
          acc[i][j] = mfma16(af[i][kk], bfr[j][kk], acc[i][j]);
  }
#pragma unroll
  for (int i = 0; i < 2; ++i)
#pragma unroll
    for (int j = 0; j < 4; ++j)
#pragma unroll
      for (int r = 0; r < 4; ++r) {
        const size_t row = bm + wr + i * 16 + l4 * 4 + r;
        const size_t col = bn + wc + j * 16 + l15;
        if constexpr (OUT_BF16)
          ((ushort*)Cv)[row * N + col] = f2b(acc[i][j][r]);
        else
          ((float*)Cv)[row * N + col] = acc[i][j][r];
      }
}

// ---------------- Flash attention v11 (R17 best): 128-key supersteps ------
#define MCONST 12.0f

__device__ __forceinline__ void astep2(const bf8 (&kfA)[4], const bf8 (&kfB)[4],
                                       const bf8 (&vfA)[4], const bf8 (&vfB)[4],
                                       const bf8 (&qf)[4], f32x16& o0,
                                       f32x16& o1, float& l, int k0, int qg,
                                       bool maskt, int hi) {
  f32x16 s0 = {}, s1 = {};
  __builtin_amdgcn_s_setprio(1);
#pragma unroll
  for (int ks = 0; ks < 4; ++ks) s0 = mfma32(kfA[ks], qf[ks], s0);
#pragma unroll
  for (int ks = 0; ks < 4; ++ks) s1 = mfma32(kfB[ks], qf[ks], s1);
  __builtin_amdgcn_s_setprio(0);
  if (maskt) {
#pragma unroll
    for (int r = 0; r < 16; ++r) {
      const int key = k0 + (r & 3) + 8 * (r >> 2) + 4 * hi;
      if (key > qg) s0[r] = -1e30f;
      if (key + 32 > qg) s1[r] = -1e30f;
    }
  }
  float t[16];
#pragma unroll
  for (int r = 0; r < 16; ++r) {
    s0[r] = fexp2(s0[r] - MCONST);
    s1[r] = fexp2(s1[r] - MCONST);
    t[r] = s0[r] + s1[r];
  }
#pragma unroll
  for (int st = 8; st > 0; st >>= 1)
#pragma unroll
    for (int r = 0; r < st; ++r) t[r] += t[r + st];
  l += t[0] + __shfl_xor(t[0], 32);
  bf8 pa[4];
  {
    uint a0 = cvtpk(s0[0], s0[1]), a1 = cvtpk(s0[2], s0[3]);
    uint b0 = cvtpk(s0[4], s0[5]), b1 = cvtpk(s0[6], s0[7]);
    plswap(a0, b0);
    plswap(a1, b1);
    i32x4 w = {(int)a0, (int)a1, (int)b0, (int)b1};
    pa[0] = __builtin_bit_cast(bf8, w);
    uint c0 = cvtpk(s0[8], s0[9]), c1 = cvtpk(s0[10], s0[11]);
    uint d0 = cvtpk(s0[12], s0[13]), d1 = cvtpk(s0[14], s0[15]);
    plswap(c0, d0);
    plswap(c1, d1);
    i32x4 w2 = {(int)c0, (int)c1, (int)d0, (int)d1};
    pa[1] = __builtin_bit_cast(bf8, w2);
  }
  {
    uint a0 = cvtpk(s1[0], s1[1]), a1 = cvtpk(s1[2], s1[3]);
    uint b0 = cvtpk(s1[4], s1[5]), b1 = cvtpk(s1[6], s1[7]);
    plswap(a0, b0);
    plswap(a1, b1);
    i32x4 w = {(int)a0, (int)a1, (int)b0, (int)b1};
    pa[2] = __builtin_bit_cast(bf8, w);
    uint c0 = cvtpk(s1[8], s1[9]), c1 = cvtpk(s1[10], s1[11]);
    uint d0 = cvtpk(s1[12], s1[13]), d1 = cvtpk(s1[14], s1[15]);
    plswap(c0, d0);
    plswap(c1, d1);
    i32x4 w2 = {(int)c0, (int)c1, (int)d0, (int)d1};
    pa[3] = __builtin_bit_cast(bf8, w2);
  }
  __builtin_amdgcn_s_setprio(1);
#pragma unroll
  for (int ks = 0; ks < 4; ++ks) o0 = mfma32(vfA[ks], pa[ks], o0);
#pragma unroll
  for (int ks = 0; ks < 4; ++ks) o1 = mfma32(vfB[ks], pa[ks], o1);
  __builtin_amdgcn_s_setprio(0);
}

__device__ __forceinline__ void tile_out(ushort* ow, const f32x16& o0,
                                         const f32x16& o1, float l, int b,
                                         int h, int qw, int l31, int hi,
                                         int lane, ushort* ao) {
  const float inv = 1.0f / l;
#pragma unroll
  for (int dt = 0; dt < 2; ++dt)
#pragma unroll
    for (int rq = 0; rq < 4; ++rq) {
      const f32x16& ac = dt ? o1 : o0;
      uint2 w;
      w.x = (uint)f2b(ac[rq * 4 + 0] * inv) |
            ((uint)f2b(ac[rq * 4 + 1] * inv) << 16);
      w.y = (uint)f2b(ac[rq * 4 + 2] * inv) |
            ((uint)f2b(ac[rq * 4 + 3] * inv) << 16);
      const int d = dt * 32 + 8 * rq + 4 * hi;
      *(uint2*)&ow[l31 * 66 + d] = w;
    }
  asm volatile("s_waitcnt lgkmcnt(0)" ::: "memory");
  __builtin_amdgcn_sched_barrier(0);
  const int rrow = lane >> 4;
  const int rcol = (lane & 15) * 4;
  const size_t gbase = ((size_t)b * 2048 + qw) * 1024 + h * 64;
#pragma unroll
  for (int i = 0; i < 8; ++i) {
    const int rw = i * 4 + rrow;
    uint2 v = *(const uint2*)&ow[rw * 66 + rcol];
    *(uint2*)&ao[gbase + (size_t)rw * 1024 + rcol] = v;
  }
}

__global__ __launch_bounds__(256) void attn_fwd(const ushort* __restrict__ qh,
                                                const ushort* __restrict__ kh,
                                                const ushort* __restrict__ vT,
                                                ushort* __restrict__ ao) {
  __shared__ ushort kls[2][4096];   // 2 x 8KB K subtiles (swizzled)
  __shared__ ushort vls[2][4096];   // 2 x 8KB V subtiles (swizzled)
  __shared__ ushort olds[4][2176];  // per-wave epilogue transpose scratch
  const int tid = threadIdx.x;
  const int wid = tid >> 6, lane = tid & 63;
  const int l31 = lane & 31, hi = lane >> 5;
  const int gid = blockIdx.x;  // 512
  const int bk = gid & 7;      // b*4 + kv (fixed per XCD -> KV L2-resident)
  const int b = bk >> 2, kv = bk & 3;
  const int rest = gid >> 3;   // 0..63
  const int p = rest & 31, half = rest >> 5;
  const int t = half ? (63 - p) : p;  // pairing: per-CU tile sum = 33
  const int h = kv * 4 + wid;
  const int n = (32 * t + 95) >> 6;   // 64-key tiles: 1..32
  const int nss = (n + 1) >> 1;       // 128-key supersteps: 1..16
  const int qg = t * 32 + l31;

  const ushort* kbase = kh + (size_t)(b * 4 + kv) * 2048 * 64;
  const ushort* vbase = vT + (size_t)(b * 4 + kv) * 64 * 2048;

  auto stageTile = [&](int j, int hf) {
    const int k0 = j * 64;
#pragma unroll
    for (int jj2 = 0; jj2 < 2; ++jj2) {
      const int jj = wid + jj2 * 4;
      const int i = jj * 64 + lane;
      const int r = i >> 3, s = i & 7;
      const int sw = (s ^ (r & 7)) << 3;
      gload16(kbase + (size_t)(k0 + r) * 64 + sw, kls[hf] + jj * 512);
      gload16(vbase + (size_t)r * 2048 + k0 + sw, vls[hf] + jj * 512);
    }
  };
  auto stageSS = [&](int ss) {
    const int j0 = 2 * ss;
    const int j1 = (2 * ss + 1 < n) ? (2 * ss + 1) : (n - 1);
    stageTile(j0, 0);
    stageTile(j1, 1);
  };

  stageSS(0);

  bf8 qf[4];
  {
    const ushort* qb = qh + ((size_t)(b * 16 + h) * 2048 + qg) * 64 + hi * 8;
#pragma unroll
    for (int ks = 0; ks < 4; ++ks) qf[ks] = *(const bf8*)(qb + ks * 16);
  }

  f32x16 o0 = {}, o1 = {};
  float l = 0.f;
  const int sw0 = l31 & 7;

  for (int ss = 0; ss < nss; ++ss) {
    asm volatile("s_waitcnt vmcnt(0)" ::: "memory");
    __builtin_amdgcn_s_barrier();
    asm volatile("" ::: "memory");
    bf8 kfA[2][4], kfB[2][4], vfA[2][4], vfB[2][4];
#pragma unroll
    for (int hf = 0; hf < 2; ++hf)
#pragma unroll
      for (int ks = 0; ks < 4; ++ks) {
        const int c2 = 2 * ks + hi;
        const int off = (c2 ^ sw0) << 3;
        kfA[hf][ks] = *(const bf8*)&kls[hf][l31 * 64 + off];
        kfB[hf][ks] = *(const bf8*)&kls[hf][(32 + l31) * 64 + off];
        vfA[hf][ks] = *(const bf8*)&vls[hf][l31 * 64 + off];
        vfB[hf][ks] = *(const bf8*)&vls[hf][(32 + l31) * 64 + off];
      }
    asm volatile("s_waitcnt lgkmcnt(0)" ::: "memory");
    __builtin_amdgcn_sched_barrier(0);
    __builtin_amdgcn_s_barrier();
    if (ss + 1 < nss) stageSS(ss + 1);
    const int j0 = 2 * ss, j1 = 2 * ss + 1;
    astep2(kfA[0], kfB[0], vfA[0], vfB[0], qf, o0, o1, l, j0 * 64, qg,
           j0 == n - 1, hi);
    if (j1 < n)
      astep2(kfA[1], kfB[1], vfA[1], vfB[1], qf, o0, o1, l, j1 * 64, qg,
             j1 == n - 1, hi);
  }
  tile_out(olds[wid], o0, o1, l, b, h, t * 32, l31, hi, lane, ao);
}

extern "C" void kernel_launch(void* const* d_in, const int* in_sizes, int n_in,
                              void* d_out, int out_size, void* d_ws,
                              size_t ws_size, hipStream_t stream) {
  (void)in_sizes; (void)n_in; (void)out_size; (void)ws_size;
  const float* x = (const float*)d_in[0];
  const float* wq = (const float*)d_in[1];
  const float* wk = (const float*)d_in[2];
  const float* wv = (const float*)d_in[3];
  const float* wo = (const float*)d_in[4];
  const float* fc = (const float*)d_in[5];
  const float* fs = (const float*)d_in[6];
  float* out = (float*)d_out;

  ushort* xb = (ushort*)d_ws;               // 4096x1024
  ushort* wqkvT = xb + 4194304;             // 1536x1024
  ushort* woT = wqkvT + 1572864;            // 1024x1024
  ushort* qkv = woT + 1048576;              // (unused now)
  ushort* qh = qkv + 6291456;               // 32x2048x64
  ushort* kh = qh + 4194304;                // 8x2048x64
  ushort* vTb = kh + 1048576;               // 8x64x2048
  ushort* ao = vTb + 1048576;               // 4096x1024

  prep1<<<6656, 256, 0, stream>>>(x, wq, wk, wv, wo, xb, wqkvT, woT);
  gemm_rope<<<768, 256, 0, stream>>>(xb, wqkvT, fc, fs, qh, kh, vTb);
  attn_fwd<<<512, 256, 0, stream>>>(qh, kh, vTb, ao);
  gemm_bt<false><<<512, 256, 0, stream>>>(ao, woT, out, 4096, 1024, 1024, 8);
}

// Round 22
// 96.578 us; speedup vs baseline: 1.1354x; 1.0148x over previous
//
#include <hip/hip_runtime.h>

typedef short bf8 __attribute__((ext_vector_type(8)));   // 8 bf16 in 4 VGPRs
typedef float f32x4 __attribute__((ext_vector_type(4)));
typedef float f32x16 __attribute__((ext_vector_type(16)));
typedef int i32x4 __attribute__((ext_vector_type(4)));

__device__ __forceinline__ ushort f2b(float f) {
  unsigned x = __builtin_bit_cast(unsigned, f);
  unsigned r = (x + 0x7fffu + ((x >> 16) & 1u)) >> 16;
  return (ushort)r;
}
__device__ __forceinline__ float b2f(ushort u) {
  unsigned x = ((unsigned)u) << 16;
  return __builtin_bit_cast(float, x);
}

__device__ __forceinline__ f32x4 mfma16(bf8 a, bf8 b, f32x4 c) {
  return __builtin_amdgcn_mfma_f32_16x16x32_bf16(a, b, c, 0, 0, 0);
}
__device__ __forceinline__ f32x16 mfma32(bf8 a, bf8 b, f32x16 c) {
  return __builtin_amdgcn_mfma_f32_32x32x16_bf16(a, b, c, 0, 0, 0);
}

__device__ __forceinline__ float fexp2(float x) {
#if __has_builtin(__builtin_amdgcn_exp2f)
  return __builtin_amdgcn_exp2f(x);
#else
  return exp2f(x);
#endif
}

__device__ __forceinline__ uint cvtpk(float lo, float hi_) {
  uint r;
  asm("v_cvt_pk_bf16_f32 %0, %1, %2" : "=v"(r) : "v"(lo), "v"(hi_));
  return r;
}
__device__ __forceinline__ void plswap(uint& a, uint& b) {
  asm("v_permlane32_swap_b32 %0, %1" : "+v"(a), "+v"(b));
}

__device__ __forceinline__ void gload16(const ushort* g, ushort* l) {
  __builtin_amdgcn_global_load_lds(
      (const __attribute__((address_space(1))) void*)g,
      (__attribute__((address_space(3))) void*)l, 16, 0, 0);
}

// ---------------- prep1: cast x (f32->bf16) + all weight transposes ------
__global__ __launch_bounds__(256) void prep1(
    const float* __restrict__ x, const float* __restrict__ wq,
    const float* __restrict__ wk, const float* __restrict__ wv,
    const float* __restrict__ wo, ushort* __restrict__ xb,
    ushort* __restrict__ wqkvT, ushort* __restrict__ woT) {
  __shared__ float tile[32][33];
  const int bid = blockIdx.x;
  if (bid < 4096) {
    const int i = (bid * 256 + threadIdx.x) * 4;
    float4 v = *(const float4*)(x + i);
    ushort4 o;
    o.x = f2b(v.x); o.y = f2b(v.y); o.z = f2b(v.z); o.w = f2b(v.w);
    *(ushort4*)(xb + i) = o;
    return;
  }
  int t = bid - 4096;  // 0..2559
  const float* src;
  ushort* dst;
  int N;
  if (t < 1024) {
    src = wq; dst = wqkvT; N = 1024;
  } else if (t < 1280) {
    src = wk; dst = wqkvT + 1024 * 1024; N = 256; t -= 1024;
  } else if (t < 1536) {
    src = wv; dst = wqkvT + 1280 * 1024; N = 256; t -= 1280;
  } else {
    src = wo; dst = woT; N = 1024; t -= 1536;
  }
  const int kx = (t & 31) * 32, nx = (t >> 5) * 32;
  const int tx = threadIdx.x & 31, ty = threadIdx.x >> 5;
#pragma unroll
  for (int i = ty; i < 32; i += 8)
    tile[i][tx] = src[(size_t)(kx + i) * N + nx + tx];
  __syncthreads();
#pragma unroll
  for (int i = ty; i < 32; i += 8)
    dst[(size_t)(nx + i) * 1024 + kx + tx] = f2b(tile[tx][i]);
}

// ------- gemm_rope: x @ wqkvT with FUSED RoPE + V-transpose epilogue ------
// 64x128 tile, BK=64, double-buffered, XCD-swizzled (768 blocks, nbx=12).
// No manual lgkm drain: frag reads are compiler loads, hipcc emits
// fine-grained lgkmcnt per dependent MFMA and can overlap read tail with
// first MFMAs. Parity safety: MFMAs (with their waits) precede next barrier.
__global__ __launch_bounds__(256) void gemm_rope(
    const ushort* __restrict__ A, const ushort* __restrict__ Bt,
    const float* __restrict__ fc, const float* __restrict__ fs,
    ushort* __restrict__ qh, ushort* __restrict__ kh,
    ushort* __restrict__ vT) {
  __shared__ ushort aL[2][64 * 64];    // 2 x 8 KB
  __shared__ ushort bL[2][128 * 64];   // 2 x 16 KB (reused for V transpose)
  const int K = 1024;
  const int tid = threadIdx.x;
  const int wid = tid >> 6, lane = tid & 63;
  const int l15 = lane & 15, l4 = lane >> 4;
  const int qch = gridDim.x >> 3;
  const int sw = (blockIdx.x & 7) * qch + (blockIdx.x >> 3);
  const int bxi = sw % 12, byi = sw / 12;
  const int bm = byi * 64, bn = bxi * 128;
  const int wr = (wid & 1) * 32, wc = (wid >> 1) * 64;
  const int nIter = K >> 6;

  auto stage = [&](int it, int par) {
    const int kb = it * 64;
#pragma unroll
    for (int i = 0; i < 2; ++i) {
      const int e = (i * 256 + tid) * 8;
      const int r = e >> 6, c = e & 63;
      gload16(A + (size_t)(bm + r) * K + kb + c,
              &aL[par][i * 2048 + wid * 512]);
    }
#pragma unroll
    for (int i = 0; i < 4; ++i) {
      const int e = (i * 256 + tid) * 8;
      const int r = e >> 6, c = e & 63;
      gload16(Bt + (size_t)(bn + r) * K + kb + c,
              &bL[par][i * 2048 + wid * 512]);
    }
  };

  stage(0, 0);
  f32x4 acc[2][4] = {};
  for (int it = 0; it < nIter; ++it) {
    const int par = it & 1;
    asm volatile("s_waitcnt vmcnt(0)" ::: "memory");
    __builtin_amdgcn_s_barrier();
    asm volatile("" ::: "memory");
    if (it + 1 < nIter) stage(it + 1, par ^ 1);
    bf8 af[2][2], bfr[4][2];
#pragma unroll
    for (int i = 0; i < 2; ++i)
#pragma unroll
      for (int kk = 0; kk < 2; ++kk)
        af[i][kk] =
            *(const bf8*)&aL[par][(wr + i * 16 + l15) * 64 + kk * 32 + l4 * 8];
#pragma unroll
    for (int j = 0; j < 4; ++j)
#pragma unroll
      for (int kk = 0; kk < 2; ++kk)
        bfr[j][kk] =
            *(const bf8*)&bL[par][(wc + j * 16 + l15) * 64 + kk * 32 + l4 * 8];
#pragma unroll
    for (int kk = 0; kk < 2; ++kk)
#pragma unroll
      for (int i = 0; i < 2; ++i)
#pragma unroll
        for (int j = 0; j < 4; ++j)
          acc[i][j] = mfma16(af[i][kk], bfr[j][kk], acc[i][j]);
  }

  if (bxi < 10) {
    // ---- Q or K: fused RoPE, direct write ----
    const bool isQ = bxi < 8;
    const float qs = isQ ? 0.18033688f : 1.0f;  // (1/8)*log2(e) for Q
    const int colbase = bn + wc;
    const int head = isQ ? (colbase >> 6) : ((colbase - 1024) >> 6);
    const int nh = isQ ? 16 : 4;
    ushort* outp = isQ ? qh : kh;
#pragma unroll
    for (int i = 0; i < 2; ++i)
#pragma unroll
      for (int j = 0; j < 4; ++j) {
        const int d = j * 16 + l15;
        const int d2 = d >> 1;
#pragma unroll
        for (int r = 0; r < 4; ++r) {
          const int row = bm + wr + i * 16 + l4 * 4 + r;
          const int s = row & 2047, bb = row >> 11;
          const float c = fc[s * 32 + d2], sn = fs[s * 32 + d2];
          const float val = acc[i][j][r];
          const float par = __shfl_xor(val, 1);
          float o;
          if ((l15 & 1) == 0)
            o = (val * c - par * sn) * qs;  // even d: tr*c - ti*s
          else
            o = (par * sn + val * c) * qs;  // odd d: tr*s + ti*c
          outp[((size_t)(bb * nh + head) * 2048 + s) * 64 + d] = f2b(o);
        }
      }
  } else {
    // ---- V: LDS transpose (reuse bL, free after K-loop) then write vT ----
    __syncthreads();  // block-uniform branch; all frag reads already in regs
    ushort* ldsT = &bL[0][0];  // 128 x 68 ushorts = 17 KB <= 32 KB
#pragma unroll
    for (int i = 0; i < 2; ++i)
#pragma unroll
      for (int j = 0; j < 4; ++j) {
        const int cl = wc + j * 16 + l15;
#pragma unroll
        for (int r = 0; r < 4; ++r) {
          const int rl = wr + i * 16 + l4 * 4 + r;
          ldsT[cl * 68 + rl] = f2b(acc[i][j][r]);
        }
      }
    __syncthreads();
    const int bb = bm >> 11, sbase = bm & 2047;
    const int dl = tid >> 1, sh = (tid & 1) * 32;
    const int gcol = bn + dl - 1280;
    const int kv = gcol >> 6, d = gcol & 63;
    ushort* dst = vT + ((size_t)(bb * 4 + kv) * 64 + d) * 2048 + sbase + sh;
    const ushort* srcl = ldsT + dl * 68 + sh;
#pragma unroll
    for (int k = 0; k < 8; ++k)
      *(uint2*)(dst + k * 4) = *(const uint2*)(srcl + k * 4);
  }
}

// ------- GEMM C[M][N]=A[M][K]*Bt[N][K]^T; 64x128, BK=64, double-buffered --
template <bool OUT_BF16>
__global__ __launch_bounds__(256) void gemm_bt(const ushort* __restrict__ A,
                                               const ushort* __restrict__ Bt,
                                               void* __restrict__ Cv, int M,
                                               int N, int K, int nbx) {
  __shared__ ushort aL[2][64 * 64];    // 2 x 8 KB
  __shared__ ushort bL[2][128 * 64];   // 2 x 16 KB
  const int tid = threadIdx.x;
  const int wid = tid >> 6, lane = tid & 63;
  const int l15 = lane & 15, l4 = lane >> 4;
  const int qch = gridDim.x >> 3;
  const int sw = (blockIdx.x & 7) * qch + (blockIdx.x >> 3);
  const int bxi = sw % nbx, byi = sw / nbx;
  const int bm = byi * 64, bn = bxi * 128;
  const int wr = (wid & 1) * 32, wc = (wid >> 1) * 64;
  const int nIter = K >> 6;

  auto stage = [&](int it, int par) {
    const int kb = it * 64;
#pragma unroll
    for (int i = 0; i < 2; ++i) {
      const int e = (i * 256 + tid) * 8;
      const int r = e >> 6, c = e & 63;
      gload16(A + (size_t)(bm + r) * K + kb + c,
              &aL[par][i * 2048 + wid * 512]);
    }
#pragma unroll
    for (int i = 0; i < 4; ++i) {
      const int e = (i * 256 + tid) * 8;
      const int r = e >> 6, c = e & 63;
      gload16(Bt + (size_t)(bn + r) * K + kb + c,
              &bL[par][i * 2048 + wid * 512]);
    }
  };

  stage(0, 0);
  f32x4 acc[2][4] = {};
  for (int it = 0; it < nIter; ++it) {
    const int par = it & 1;
    asm volatile("s_waitcnt vmcnt(0)" ::: "memory");
    __builtin_amdgcn_s_barrier();
    asm volatile("" ::: "memory");
    if (it + 1 < nIter) stage(it + 1, par ^ 1);
    bf8 af[2][2], bfr[4][2];
#pragma unroll
    for (int i = 0; i < 2; ++i)
#pragma unroll
      for (int kk = 0; kk < 2; ++kk)
        af[i][kk] =
            *(const bf8*)&aL[par][(wr + i * 16 + l15) * 64 + kk * 32 + l4 * 8];
#pragma unroll
    for (int j = 0; j < 4; ++j)
#pragma unroll
      for (int kk = 0; kk < 2; ++kk)
        bfr[j][kk] =
            *(const bf8*)&bL[par][(wc + j * 16 + l15) * 64 + kk * 32 + l4 * 8];
#pragma unroll
    for (int kk = 0; kk < 2; ++kk)
#pragma unroll
      for (int i = 0; i < 2; ++i)
#pragma unroll
        for (int j = 0; j < 4; ++j)
          acc[i][j] = mfma16(af[i][kk], bfr[j][kk], acc[i][j]);
  }
#pragma unroll
  for (int i = 0; i < 2; ++i)
#pragma unroll
    for (int j = 0; j < 4; ++j)
#pragma unroll
      for (int r = 0; r < 4; ++r) {
        const size_t row = bm + wr + i * 16 + l4 * 4 + r;
        const size_t col = bn + wc + j * 16 + l15;
        if constexpr (OUT_BF16)
          ((ushort*)Cv)[row * N + col] = f2b(acc[i][j][r]);
        else
          ((float*)Cv)[row * N + col] = acc[i][j][r];
      }
}

// ---------------- Flash attention v11 (R17 best): 128-key supersteps ------
// No setprio: 4 waves are barrier-locked in identical phases (T5 requires
// role diversity; m190 lockstep analog measured setprio negative).
#define MCONST 12.0f

__device__ __forceinline__ void astep2(const bf8 (&kfA)[4], const bf8 (&kfB)[4],
                                       const bf8 (&vfA)[4], const bf8 (&vfB)[4],
                                       const bf8 (&qf)[4], f32x16& o0,
                                       f32x16& o1, float& l, int k0, int qg,
                                       bool maskt, int hi) {
  f32x16 s0 = {}, s1 = {};
#pragma unroll
  for (int ks = 0; ks < 4; ++ks) s0 = mfma32(kfA[ks], qf[ks], s0);
#pragma unroll
  for (int ks = 0; ks < 4; ++ks) s1 = mfma32(kfB[ks], qf[ks], s1);
  if (maskt) {
#pragma unroll
    for (int r = 0; r < 16; ++r) {
      const int key = k0 + (r & 3) + 8 * (r >> 2) + 4 * hi;
      if (key > qg) s0[r] = -1e30f;
      if (key + 32 > qg) s1[r] = -1e30f;
    }
  }
  float t[16];
#pragma unroll
  for (int r = 0; r < 16; ++r) {
    s0[r] = fexp2(s0[r] - MCONST);
    s1[r] = fexp2(s1[r] - MCONST);
    t[r] = s0[r] + s1[r];
  }
#pragma unroll
  for (int st = 8; st > 0; st >>= 1)
#pragma unroll
    for (int r = 0; r < st; ++r) t[r] += t[r + st];
  l += t[0] + __shfl_xor(t[0], 32);
  bf8 pa[4];
  {
    uint a0 = cvtpk(s0[0], s0[1]), a1 = cvtpk(s0[2], s0[3]);
    uint b0 = cvtpk(s0[4], s0[5]), b1 = cvtpk(s0[6], s0[7]);
    plswap(a0, b0);
    plswap(a1, b1);
    i32x4 w = {(int)a0, (int)a1, (int)b0, (int)b1};
    pa[0] = __builtin_bit_cast(bf8, w);
    uint c0 = cvtpk(s0[8], s0[9]), c1 = cvtpk(s0[10], s0[11]);
    uint d0 = cvtpk(s0[12], s0[13]), d1 = cvtpk(s0[14], s0[15]);
    plswap(c0, d0);
    plswap(c1, d1);
    i32x4 w2 = {(int)c0, (int)c1, (int)d0, (int)d1};
    pa[1] = __builtin_bit_cast(bf8, w2);
  }
  {
    uint a0 = cvtpk(s1[0], s1[1]), a1 = cvtpk(s1[2], s1[3]);
    uint b0 = cvtpk(s1[4], s1[5]), b1 = cvtpk(s1[6], s1[7]);
    plswap(a0, b0);
    plswap(a1, b1);
    i32x4 w = {(int)a0, (int)a1, (int)b0, (int)b1};
    pa[2] = __builtin_bit_cast(bf8, w);
    uint c0 = cvtpk(s1[8], s1[9]), c1 = cvtpk(s1[10], s1[11]);
    uint d0 = cvtpk(s1[12], s1[13]), d1 = cvtpk(s1[14], s1[15]);
    plswap(c0, d0);
    plswap(c1, d1);
    i32x4 w2 = {(int)c0, (int)c1, (int)d0, (int)d1};
    pa[3] = __builtin_bit_cast(bf8, w2);
  }
#pragma unroll
  for (int ks = 0; ks < 4; ++ks) o0 = mfma32(vfA[ks], pa[ks], o0);
#pragma unroll
  for (int ks = 0; ks < 4; ++ks) o1 = mfma32(vfB[ks], pa[ks], o1);
}

__device__ __forceinline__ void tile_out(ushort* ow, const f32x16& o0,
                                         const f32x16& o1, float l, int b,
                                         int h, int qw, int l31, int hi,
                                         int lane, ushort* ao) {
  const float inv = 1.0f / l;
#pragma unroll
  for (int dt = 0; dt < 2; ++dt)
#pragma unroll
    for (int rq = 0; rq < 4; ++rq) {
      const f32x16& ac = dt ? o1 : o0;
      uint2 w;
      w.x = (uint)f2b(ac[rq * 4 + 0] * inv) |
            ((uint)f2b(ac[rq * 4 + 1] * inv) << 16);
      w.y = (uint)f2b(ac[rq * 4 + 2] * inv) |
            ((uint)f2b(ac[rq * 4 + 3] * inv) << 16);
      const int d = dt * 32 + 8 * rq + 4 * hi;
      *(uint2*)&ow[l31 * 66 + d] = w;
    }
  asm volatile("s_waitcnt lgkmcnt(0)" ::: "memory");
  __builtin_amdgcn_sched_barrier(0);
  const int rrow = lane >> 4;
  const int rcol = (lane & 15) * 4;
  const size_t gbase = ((size_t)b * 2048 + qw) * 1024 + h * 64;
#pragma unroll
  for (int i = 0; i < 8; ++i) {
    const int rw = i * 4 + rrow;
    uint2 v = *(const uint2*)&ow[rw * 66 + rcol];
    *(uint2*)&ao[gbase + (size_t)rw * 1024 + rcol] = v;
  }
}

__global__ __launch_bounds__(256) void attn_fwd(const ushort* __restrict__ qh,
                                                const ushort* __restrict__ kh,
                                                const ushort* __restrict__ vT,
                                                ushort* __restrict__ ao) {
  __shared__ ushort kls[2][4096];   // 2 x 8KB K subtiles (swizzled)
  __shared__ ushort vls[2][4096];   // 2 x 8KB V subtiles (swizzled)
  __shared__ ushort olds[4][2176];  // per-wave epilogue transpose scratch
  const int tid = threadIdx.x;
  const int wid = tid >> 6, lane = tid & 63;
  const int l31 = lane & 31, hi = lane >> 5;
  const int gid = blockIdx.x;  // 512
  const int bk = gid & 7;      // b*4 + kv (fixed per XCD -> KV L2-resident)
  const int b = bk >> 2, kv = bk & 3;
  const int rest = gid >> 3;   // 0..63
  const int p = rest & 31, half = rest >> 5;
  const int t = half ? (63 - p) : p;  // pairing: per-CU tile sum = 33
  const int h = kv * 4 + wid;
  const int n = (32 * t + 95) >> 6;   // 64-key tiles: 1..32
  const int nss = (n + 1) >> 1;       // 128-key supersteps: 1..16
  const int qg = t * 32 + l31;

  const ushort* kbase = kh + (size_t)(b * 4 + kv) * 2048 * 64;
  const ushort* vbase = vT + (size_t)(b * 4 + kv) * 64 * 2048;

  auto stageTile = [&](int j, int hf) {
    const int k0 = j * 64;
#pragma unroll
    for (int jj2 = 0; jj2 < 2; ++jj2) {
      const int jj = wid + jj2 * 4;
      const int i = jj * 64 + lane;
      const int r = i >> 3, s = i & 7;
      const int sw = (s ^ (r & 7)) << 3;
      gload16(kbase + (size_t)(k0 + r) * 64 + sw, kls[hf] + jj * 512);
      gload16(vbase + (size_t)r * 2048 + k0 + sw, vls[hf] + jj * 512);
    }
  };
  auto stageSS = [&](int ss) {
    const int j0 = 2 * ss;
    const int j1 = (2 * ss + 1 < n) ? (2 * ss + 1) : (n - 1);
    stageTile(j0, 0);
    stageTile(j1, 1);
  };

  stageSS(0);

  bf8 qf[4];
  {
    const ushort* qb = qh + ((size_t)(b * 16 + h) * 2048 + qg) * 64 + hi * 8;
#pragma unroll
    for (int ks = 0; ks < 4; ++ks) qf[ks] = *(const bf8*)(qb + ks * 16);
  }

  f32x16 o0 = {}, o1 = {};
  float l = 0.f;
  const int sw0 = l31 & 7;

  for (int ss = 0; ss < nss; ++ss) {
    asm volatile("s_waitcnt vmcnt(0)" ::: "memory");
    __builtin_amdgcn_s_barrier();
    asm volatile("" ::: "memory");
    bf8 kfA[2][4], kfB[2][4], vfA[2][4], vfB[2][4];
#pragma unroll
    for (int hf = 0; hf < 2; ++hf)
#pragma unroll
      for (int ks = 0; ks < 4; ++ks) {
        const int c2 = 2 * ks + hi;
        const int off = (c2 ^ sw0) << 3;
        kfA[hf][ks] = *(const bf8*)&kls[hf][l31 * 64 + off];
        kfB[hf][ks] = *(const bf8*)&kls[hf][(32 + l31) * 64 + off];
        vfA[hf][ks] = *(const bf8*)&vls[hf][l31 * 64 + off];
        vfB[hf][ks] = *(const bf8*)&vls[hf][(32 + l31) * 64 + off];
      }
    asm volatile("s_waitcnt lgkmcnt(0)" ::: "memory");
    __builtin_amdgcn_sched_barrier(0);
    __builtin_amdgcn_s_barrier();  // all reads drained -> safe overwrite
    if (ss + 1 < nss) stageSS(ss + 1);
    const int j0 = 2 * ss, j1 = 2 * ss + 1;
    astep2(kfA[0], kfB[0], vfA[0], vfB[0], qf, o0, o1, l, j0 * 64, qg,
           j0 == n - 1, hi);
    if (j1 < n)
      astep2(kfA[1], kfB[1], vfA[1], vfB[1], qf, o0, o1, l, j1 * 64, qg,
             j1 == n - 1, hi);
  }
  tile_out(olds[wid], o0, o1, l, b, h, t * 32, l31, hi, lane, ao);
}

extern "C" void kernel_launch(void* const* d_in, const int* in_sizes, int n_in,
                              void* d_out, int out_size, void* d_ws,
                              size_t ws_size, hipStream_t stream) {
  (void)in_sizes; (void)n_in; (void)out_size; (void)ws_size;
  const float* x = (const float*)d_in[0];
  const float* wq = (const float*)d_in[1];
  const float* wk = (const float*)d_in[2];
  const float* wv = (const float*)d_in[3];
  const float* wo = (const float*)d_in[4];
  const float* fc = (const float*)d_in[5];
  const float* fs = (const float*)d_in[6];
  float* out = (float*)d_out;

  ushort* xb = (ushort*)d_ws;               // 4096x1024
  ushort* wqkvT = xb + 4194304;             // 1536x1024
  ushort* woT = wqkvT + 1572864;            // 1024x1024
  ushort* qkv = woT + 1048576;              // (unused now)
  ushort* qh = qkv + 6291456;               // 32x2048x64
  ushort* kh = qh + 4194304;                // 8x2048x64
  ushort* vTb = kh + 1048576;               // 8x64x2048
  ushort* ao = vTb + 1048576;               // 4096x1024

  prep1<<<6656, 256, 0, stream>>>(x, wq, wk, wv, wo, xb, wqkvT, woT);
  gemm_rope<<<768, 256, 0, stream>>>(xb, wqkvT, fc, fs, qh, kh, vTb);
  attn_fwd<<<512, 256, 0, stream>>>(qh, kh, vTb, ao);
  gemm_bt<false><<<512, 256, 0, stream>>>(ao, woT, out, 4096, 1024, 1024, 8);
}